// Round 2
// baseline (5065.245 us; speedup 1.0000x reference)
//
#include <hip/hip_runtime.h>
#include <stdint.h>

// ============================================================================
// JAX threefry2x32 PRNG reproduction (partitionable semantics, verified R0).
// ============================================================================
struct U2 { unsigned a, b; };

__device__ __forceinline__ unsigned rotl32(unsigned v, int r) {
  return (v << r) | (v >> (32 - r));
}

__device__ __forceinline__ U2 tf(U2 k, unsigned x0, unsigned x1) {
  unsigned ks0 = k.a, ks1 = k.b, ks2 = k.a ^ k.b ^ 0x1BD11BDAu;
  x0 += ks0; x1 += ks1;
#define TFG(RA, RB, RC, RD, KA, KB, INC)                  \
  x0 += x1; x1 = rotl32(x1, RA); x1 ^= x0;                \
  x0 += x1; x1 = rotl32(x1, RB); x1 ^= x0;                \
  x0 += x1; x1 = rotl32(x1, RC); x1 ^= x0;                \
  x0 += x1; x1 = rotl32(x1, RD); x1 ^= x0;                \
  x0 += KA; x1 += KB + INC;
  TFG(13, 15, 26, 6, ks1, ks2, 1u)
  TFG(17, 29, 16, 24, ks2, ks0, 2u)
  TFG(13, 15, 26, 6, ks0, ks1, 3u)
  TFG(17, 29, 16, 24, ks1, ks2, 4u)
  TFG(13, 15, 26, 6, ks2, ks0, 5u)
#undef TFG
  U2 r; r.a = x0; r.b = x1; return r;
}

__device__ __forceinline__ U2 split_key(U2 key, int num, int j) {
  (void)num;
  return tf(key, 0u, (unsigned)j);
}
__device__ __forceinline__ unsigned random_bits(U2 key, int n, unsigned e) {
  (void)n;
  U2 r = tf(key, 0u, e);
  return r.a ^ r.b;
}

__device__ __forceinline__ U2 root_key() { U2 k; k.a = 0u; k.b = 42u; return k; }

__device__ __forceinline__ float jax_uniform(U2 key, int n, unsigned e,
                                             float minv, float maxv) {
  unsigned b = random_bits(key, n, e);
  float u = __uint_as_float((b >> 9) | 0x3f800000u) - 1.0f;
  float r = u * (maxv - minv) + minv;
  return fmaxf(minv, r);
}

#define ROTR 0.7853981633974483f

__device__ __forceinline__ void compute_R(float vx, float vy, float vz,
                                          float R[3][3]) {
  float nsq = vx * vx + vy * vy + vz * vz;
  float theta = sqrtf(nsq);
  if (theta < 1e-8f) {
    R[0][0] = 1.f; R[0][1] = 0.f; R[0][2] = 0.f;
    R[1][0] = 0.f; R[1][1] = 1.f; R[1][2] = 0.f;
    R[2][0] = 0.f; R[2][1] = 0.f; R[2][2] = 1.f;
    return;
  }
  float m = fmaxf(theta, 1e-8f);
  float kx = vx / m, ky = vy / m, kz = vz / m;
  float s = sinf(theta), c = cosf(theta);
  float K[3][3] = {{0.f, -kz, ky}, {kz, 0.f, -kx}, {-ky, kx, 0.f}};
  float K2[3][3];
#pragma unroll
  for (int i = 0; i < 3; i++)
#pragma unroll
    for (int j = 0; j < 3; j++)
      K2[i][j] = fmaf(K[i][2], K[2][j], fmaf(K[i][1], K[1][j], K[i][0] * K[0][j]));
  float omc = 1.0f - c;
#pragma unroll
  for (int i = 0; i < 3; i++)
#pragma unroll
    for (int j = 0; j < 3; j++)
      R[i][j] = ((i == j) ? 1.0f : 0.0f) + s * K[i][j] + omc * K2[i][j];
}

// composite sort key for stream s (0:src r1, 1:src r2, 2:tgt r1, 3:tgt r2)
__device__ __forceinline__ unsigned long long make_composite(int s, int i) {
  U2 root = root_key();
  U2 kp = split_key(root, 5, s >> 1);
  U2 key;
  if ((s & 1) == 0) {
    key = split_key(kp, 2, 1);
  } else {
    U2 kA = split_key(kp, 2, 0);
    key = split_key(kA, 2, 1);
  }
  unsigned rb = random_bits(key, 16384, (unsigned)i);
  return ((unsigned long long)rb << 32) | (unsigned)i;
}

// ============================================================================
// Agent-scope (device) atomic access helpers — persistent-kernel cross-block
// communication must bypass the non-coherent per-CU L1 / per-XCD L2.
// ============================================================================
__device__ __forceinline__ float gload(const float* p) {
  return __hip_atomic_load(const_cast<float*>(p), __ATOMIC_RELAXED,
                           __HIP_MEMORY_SCOPE_AGENT);
}
__device__ __forceinline__ void gstore(float* p, float v) {
  __hip_atomic_store(p, v, __ATOMIC_RELAXED, __HIP_MEMORY_SCOPE_AGENT);
}

// ============================================================================
// Bucket-sort rank pipeline (verified R3-R6/R10) — WIDE dispatches.
// rank_kernel fuses the round-1 inverse scatter (even streams -> x1buf).
// ============================================================================
__global__ __launch_bounds__(256) void hist_kernel(unsigned* __restrict__ hist) {
  int gid = blockIdx.x * 256 + threadIdx.x;  // 65536
  int s = gid >> 14, i = gid & 16383;
  unsigned long long c = make_composite(s, i);
  unsigned bucket = (unsigned)(c >> 56);
  atomicAdd(&hist[s * 256 + bucket], 1u);
}

__global__ __launch_bounds__(256) void prefix_kernel(
    const unsigned* __restrict__ hist, unsigned* __restrict__ base,
    unsigned* __restrict__ cursor) {
  __shared__ unsigned h[4][256];
  int t = threadIdx.x;
#pragma unroll
  for (int s = 0; s < 4; s++) h[s][t] = hist[s * 256 + t];
  __syncthreads();
#pragma unroll
  for (int s = 0; s < 4; s++) {
    unsigned acc = 0;
    for (int j = 0; j < 256; j++) acc += (j < t) ? h[s][j] : 0u;
    base[s * 256 + t] = acc;
    cursor[s * 256 + t] = acc;
  }
}

__global__ __launch_bounds__(256) void scatterb_kernel(
    unsigned* __restrict__ cursor, unsigned long long* __restrict__ sorted) {
  int gid = blockIdx.x * 256 + threadIdx.x;  // 65536
  int s = gid >> 14, i = gid & 16383;
  unsigned long long c = make_composite(s, i);
  unsigned bucket = (unsigned)(c >> 56);
  unsigned pos = atomicAdd(&cursor[s * 256 + bucket], 1u);
  sorted[(s << 14) + pos] = c;
}

// rank; even streams (round 1) scatter x1 directly: x1[perm][rank] = i;
// odd streams (round 2) store rank for idx_kernel.
__global__ __launch_bounds__(256) void rank_kernel(
    const unsigned long long* __restrict__ sorted,
    const unsigned* __restrict__ base, const unsigned* __restrict__ hist,
    unsigned* __restrict__ rank_all, unsigned* __restrict__ x1buf) {
  int gid = blockIdx.x * 256 + threadIdx.x;  // 65536
  int s = gid >> 14, k = gid & 16383;
  unsigned long long c = sorted[(s << 14) + k];
  unsigned bucket = (unsigned)(c >> 56);
  unsigned b0 = base[s * 256 + bucket];
  unsigned cnt = hist[s * 256 + bucket];
  unsigned less = 0;
  for (unsigned j = 0; j < cnt; j++)
    less += (sorted[(s << 14) + b0 + j] < c) ? 1u : 0u;
  unsigned i = (unsigned)(c & 0xffffffffull);
  unsigned rank = b0 + less;
  if ((s & 1) == 0) x1buf[((s >> 1) << 14) + rank] = i;
  else              rank_all[(s << 14) + i] = rank;
}

__global__ __launch_bounds__(256) void idx_kernel(
    const unsigned* __restrict__ rank_all, const unsigned* __restrict__ x1buf,
    int* __restrict__ idx) {
  int gid = blockIdx.x * 256 + threadIdx.x;  // 32768
  int perm = gid >> 14, i = gid & 16383;
  unsigned r = rank_all[((perm * 2 + 1) << 14) + i];
  if (r < 128u) idx[perm * 128 + (int)r] = (int)x1buf[(perm << 14) + i];
}

// ============================================================================
// setup (blocks 0..31) + DE-schedule precompute (blocks 32..991).
// pack = i1 | i2<<6 | i3<<12 | mask<<18 ; STRIDED loops (verified R9/R10).
// ============================================================================
__global__ __launch_bounds__(128) void setupperm_kernel(
    const float* __restrict__ source, const float* __restrict__ target,
    const int* __restrict__ idx, float* __restrict__ src,
    float* __restrict__ tgt, float* __restrict__ yn,
    unsigned* __restrict__ packg) {
  int blk = blockIdx.x;
  int tid = threadIdx.x;
  if (blk < 32) {
    int b = blk;
    int is = idx[tid], it = idx[128 + tid];
#pragma unroll
    for (int d = 0; d < 3; d++)
      src[(b * 128 + tid) * 3 + d] = source[((size_t)b * 16384 + is) * 3 + d];
    float y0 = target[((size_t)b * 16384 + it) * 3 + 0];
    float y1 = target[((size_t)b * 16384 + it) * 3 + 1];
    float y2 = target[((size_t)b * 16384 + it) * 3 + 2];
    tgt[(b * 128 + tid) * 3 + 0] = y0;
    tgt[(b * 128 + tid) * 3 + 1] = y1;
    tgt[(b * 128 + tid) * 3 + 2] = y2;
    yn[b * 128 + tid] = y0 * y0 + y1 * y1 + y2 * y2;
    return;
  }
  int blk2 = blk - 32;  // 960
  int it = blk2 >> 5, b = blk2 & 31;
  __shared__ unsigned pbits[3][64];
  __shared__ int lperm[3][64];
  U2 root = root_key();
  U2 kloop = split_key(root, 5, 4);
  U2 kit = split_key(kloop, 30, it);
  U2 ka = split_key(kit, 3, 0);
  for (int e = tid; e < 150; e += 128) {
    int r = e / 50, q = e % 50;
    U2 pk = split_key(ka, 96, r * 32 + b);
    U2 sub = split_key(pk, 2, 1);
    pbits[r][q] = random_bits(sub, 50, (unsigned)q);
  }
  __syncthreads();
  for (int e = tid; e < 150; e += 128) {
    int r = e / 50, q = e % 50;
    unsigned bq = pbits[r][q];
    int cnt = 0;
    for (int j = 0; j < 50; j++) {
      unsigned bj = pbits[r][j];
      cnt += (bj < bq || (bj == bq && j < q)) ? 1 : 0;
    }
    lperm[r][cnt] = q;
  }
  __syncthreads();
  if (tid < 50) {
    int p = tid, bp = b * 50 + p;
    U2 kb = split_key(kit, 3, 1);
    U2 kc = split_key(kit, 3, 2);
    U2 kc1 = split_key(kc, 2, 0), kc2 = split_key(kc, 2, 1);
    unsigned hb = random_bits(kc1, 1600, (unsigned)bp);
    unsigned lb = random_bits(kc2, 1600, (unsigned)bp);
    int jr = (int)((((hb % 6u) * 4u) + (lb % 6u)) % 6u);
    unsigned mask = 0;
#pragma unroll
    for (int d = 0; d < 6; d++) {
      unsigned rb = random_bits(kb, 9600, (unsigned)(bp * 6 + d));
      float u = __uint_as_float((rb >> 9) | 0x3f800000u) - 1.0f;
      if ((u < 0.9f) || (d == jr)) mask |= (1u << d);
    }
    unsigned pack = (unsigned)lperm[0][p] | ((unsigned)lperm[1][p] << 6) |
                    ((unsigned)lperm[2][p] << 12) | (mask << 18);
    packg[(it * 32 + b) * 50 + p] = pack;
  }
}

// ============================================================================
// Chamfer eval core (verified R6 — bitwise identical d2/min/sum path).
// ============================================================================
__device__ __forceinline__ float eval_pose_core(
    float p0, float p1, float p2, float p3, float p4, float p5,
    float s0, float s1, float s2, int tid, const float4* syv, float4* xsv,
    float* rowpart, float* red1, float* red2) {
  float Rm[3][3];
  compute_R(p0, p1, p2, Rm);
  float x0 = fmaf(Rm[0][2], s2, fmaf(Rm[0][1], s1, Rm[0][0] * s0)) + p3;
  float x1 = fmaf(Rm[1][2], s2, fmaf(Rm[1][1], s1, Rm[1][0] * s0)) + p4;
  float x2 = fmaf(Rm[2][2], s2, fmaf(Rm[2][1], s1, Rm[2][0] * s0)) + p5;
  float xn = x0 * x0 + x1 * x1 + x2 * x2;
  xsv[tid] = make_float4(x0, x1, x2, xn);
  __syncthreads();
  int rg = tid & 31, cq = tid >> 5;
  float4 xr0 = xsv[4 * rg + 0];
  float4 xr1 = xsv[4 * rg + 1];
  float4 xr2 = xsv[4 * rg + 2];
  float4 xr3 = xsv[4 * rg + 3];
  float racc0 = 3.402823466e38f, racc1 = 3.402823466e38f;
  float racc2 = 3.402823466e38f, racc3 = 3.402823466e38f;
  float cacc[32];
#pragma unroll
  for (int cj = 0; cj < 32; cj++) {
    float4 y = syv[(cq << 5) + cj];
    float cr0 = fmaf(xr0.z, y.z, fmaf(xr0.y, y.y, xr0.x * y.x));
    float d0 = (xr0.w + y.w) - 2.0f * cr0; d0 = fmaxf(d0, 0.0f);
    float cr1 = fmaf(xr1.z, y.z, fmaf(xr1.y, y.y, xr1.x * y.x));
    float d1 = (xr1.w + y.w) - 2.0f * cr1; d1 = fmaxf(d1, 0.0f);
    float cr2 = fmaf(xr2.z, y.z, fmaf(xr2.y, y.y, xr2.x * y.x));
    float d2_ = (xr2.w + y.w) - 2.0f * cr2; d2_ = fmaxf(d2_, 0.0f);
    float cr3 = fmaf(xr3.z, y.z, fmaf(xr3.y, y.y, xr3.x * y.x));
    float d3 = (xr3.w + y.w) - 2.0f * cr3; d3 = fmaxf(d3, 0.0f);
    racc0 = fminf(racc0, d0); racc1 = fminf(racc1, d1);
    racc2 = fminf(racc2, d2_); racc3 = fminf(racc3, d3);
    cacc[cj] = fminf(fminf(d0, d1), fminf(d2_, d3));
  }
  rowpart[cq * 128 + 4 * rg + 0] = racc0;
  rowpart[cq * 128 + 4 * rg + 1] = racc1;
  rowpart[cq * 128 + 4 * rg + 2] = racc2;
  rowpart[cq * 128 + 4 * rg + 3] = racc3;
#pragma unroll
  for (int m = 16; m >= 1; m >>= 1) {
    bool hi = (rg & m) != 0;
#pragma unroll
    for (int j = 0; j < m; j++) {
      float lo_v = cacc[j], hi_v = cacc[j + m];
      float mine = hi ? hi_v : lo_v;
      float send = hi ? lo_v : hi_v;
      float recv = __shfl_xor(send, m, 64);
      cacc[j] = fminf(mine, recv);
    }
  }
  float colmin = cacc[0];
  __syncthreads();
  float rv = rowpart[tid];
  rv = fminf(rv, rowpart[128 + tid]);
  rv = fminf(rv, rowpart[256 + tid]);
  rv = fminf(rv, rowpart[384 + tid]);
  red1[tid] = rv;
  red2[tid] = colmin;
  __syncthreads();
  int l = tid & 63;
  float v1 = red1[l] + red1[l + 64];
  float v2 = red2[l] + red2[l + 64];
#pragma unroll
  for (int m = 32; m >= 1; m >>= 1) {
    v1 += __shfl_xor(v1, m, 64);
    v2 += __shfl_xor(v2, m, 64);
  }
  return v1 * 0.0078125f + v2 * 0.0078125f;
}

// effective pop through agent-scope loads (cross-block, persistent kernel)
__device__ __forceinline__ float eff_pop_g(const float* pop_prev,
                                           const float* fit_prev,
                                           const float* trial_prev,
                                           const float* tfit_prev,
                                           int bq, int d) {
  float f = gload(&fit_prev[bq]);
  float tfv = gload(&tfit_prev[bq]);
  return (tfv < f) ? gload(&trial_prev[bq * 6 + d])
                   : gload(&pop_prev[bq * 6 + d]);
}

// pop0 value for particle r, dim d of batch b (pure function)
__device__ __forceinline__ float pop0_val(int b, int r, int d) {
  if (r == 0) return 0.0f;
  U2 root = root_key();
  unsigned ridx = (unsigned)((b * 50 + r) * 3 + (d % 3));
  if (d < 3) {
    U2 k2 = split_key(root, 5, 2);
    return jax_uniform(k2, 4800, ridx, -ROTR, ROTR);
  }
  U2 k3 = split_key(root, 5, 3);
  return jax_uniform(k3, 4800, ridx, -1.0f, 1.0f);
}

// ============================================================================
// Persistent kernel: all 30 DE iterations + final select/transform.
// PLAIN launch (R1's cooperative launch failed silently; out stayed zero).
// Residency guarantee by construction: __launch_bounds__(128,4) ->
//   <=128 VGPR -> 16 waves/CU -> 8 blocks/CU; LDS 7.4KB -> 21 blocks/CU;
//   capacity 8*256 = 2048 >= grid 1600, so every block is resident and the
//   per-batch spin barriers (50 arrivals, monotonic, agent-scope) cannot
//   deadlock. Communication is per-batch only (donors are within batch b).
// ============================================================================
__global__ __launch_bounds__(128, 4) void de_loop_kernel(
    const float* __restrict__ srcb, const float* __restrict__ tgtb,
    const float* __restrict__ ynb, const unsigned* __restrict__ packg,
    float* __restrict__ popA, float* __restrict__ fitA,
    float* __restrict__ trialA, float* __restrict__ tfitA,
    float* __restrict__ popB, float* __restrict__ fitB,
    float* __restrict__ trialB, float* __restrict__ tfitB,
    unsigned* __restrict__ bar, float* __restrict__ Rbest,
    const float* __restrict__ source, float* __restrict__ out) {
  int blk = blockIdx.x;
  int b = blk / 50, p = blk % 50;
  int bp = blk;
  int tid = threadIdx.x;
  __shared__ float strial[8];
  __shared__ float pv4[4][6];
  __shared__ float4 syv[128];
  __shared__ float4 xsv[128];
  __shared__ float rowpart[512];
  __shared__ float red1[128];
  __shared__ float red2[128];
  __shared__ float Rsh2[12];

  {
    float y0 = tgtb[(b * 128 + tid) * 3 + 0];
    float y1 = tgtb[(b * 128 + tid) * 3 + 1];
    float y2 = tgtb[(b * 128 + tid) * 3 + 2];
    syv[tid] = make_float4(y0, y1, y2, ynb[b * 128 + tid]);
  }
  float s0 = srcb[(b * 128 + tid) * 3 + 0];
  float s1 = srcb[(b * 128 + tid) * 3 + 1];
  float s2 = srcb[(b * 128 + tid) * 3 + 2];

  for (int it = 0; it < 30; it++) {
    float* cp  = (it & 1) ? popB : popA;
    float* cf  = (it & 1) ? fitB : fitA;
    float* ct  = (it & 1) ? trialB : trialA;
    float* ctf = (it & 1) ? tfitB : tfitA;
    const float* pp  = (it & 1) ? popA : popB;
    const float* pf  = (it & 1) ? fitA : fitB;
    const float* pt  = (it & 1) ? trialA : trialB;
    const float* ptf = (it & 1) ? tfitA : tfitB;

    unsigned pack = packg[(it * 32 + b) * 50 + p];
    int i1 = (int)(pack & 63u);
    int i2 = (int)((pack >> 6) & 63u);
    int i3 = (int)((pack >> 12) & 63u);
    unsigned mask = (pack >> 18) & 63u;

    if (it == 0) {
      if (tid < 24) {
        int u = tid / 6, d = tid % 6;
        int rows[4] = {p, i1, i2, i3};
        pv4[u][d] = pop0_val(b, rows[u], d);
      }
      __syncthreads();
      float f0 = eval_pose_core(pv4[0][0], pv4[0][1], pv4[0][2], pv4[0][3],
                                pv4[0][4], pv4[0][5],
                                s0, s1, s2, tid, syv, xsv, rowpart, red1, red2);
      if (tid == 0) gstore(&cf[bp], f0);
      if (tid < 6) {
        int d = tid;
        float mu = pv4[1][d] + 0.8f * (pv4[2][d] - pv4[3][d]);
        if (d < 3) mu = fminf(fmaxf(mu, -ROTR), ROTR);
        else       mu = fminf(fmaxf(mu, -1.0f), 1.0f);
        float pv = pv4[0][d];
        float tv = ((mask >> d) & 1u) ? mu : pv;
        strial[d] = tv;
        gstore(&ct[bp * 6 + d], tv);
        gstore(&cp[bp * 6 + d], pv);
      }
      __syncthreads();
      float f = eval_pose_core(strial[0], strial[1], strial[2], strial[3],
                               strial[4], strial[5],
                               s0, s1, s2, tid, syv, xsv, rowpart, red1, red2);
      if (tid == 0) gstore(&ctf[bp], f);
    } else {
      if (tid < 6) {
        int d = tid;
        float x1v = eff_pop_g(pp, pf, pt, ptf, b * 50 + i1, d);
        float x2v = eff_pop_g(pp, pf, pt, ptf, b * 50 + i2, d);
        float x3v = eff_pop_g(pp, pf, pt, ptf, b * 50 + i3, d);
        float mu = x1v + 0.8f * (x2v - x3v);
        if (d < 3) mu = fminf(fmaxf(mu, -ROTR), ROTR);
        else       mu = fminf(fmaxf(mu, -1.0f), 1.0f);
        float pv = eff_pop_g(pp, pf, pt, ptf, bp, d);
        float tv = ((mask >> d) & 1u) ? mu : pv;
        strial[d] = tv;
        gstore(&ct[bp * 6 + d], tv);
        gstore(&cp[bp * 6 + d], pv);
      } else if (tid == 6) {
        float f = gload(&pf[bp]), tfv = gload(&ptf[bp]);
        gstore(&cf[bp], (tfv < f) ? tfv : f);
      }
      __syncthreads();
      float f = eval_pose_core(strial[0], strial[1], strial[2], strial[3],
                               strial[4], strial[5],
                               s0, s1, s2, tid, syv, xsv, rowpart, red1, red2);
      if (tid == 0) gstore(&ctf[bp], f);
    }

    // --- per-batch barrier (monotonic, agent-scope) ---
    __syncthreads();  // all block stores issued + drained before release
    if (tid == 0) {
      __hip_atomic_fetch_add(&bar[b], 1u, __ATOMIC_RELEASE,
                             __HIP_MEMORY_SCOPE_AGENT);
      unsigned tgtc = 50u * (unsigned)(it + 1);
      while (__hip_atomic_load(&bar[b], __ATOMIC_ACQUIRE,
                               __HIP_MEMORY_SCOPE_AGENT) < tgtc)
        __builtin_amdgcn_s_sleep(2);
    }
    __syncthreads();
  }

  // ==== final selection (block p==0 of each batch), per-batch release ====
  // it=29 (odd) wrote the B buffers.
  if (p == 0 && tid == 0) {
    float best = fminf(gload(&fitB[b * 50 + 0]), gload(&tfitB[b * 50 + 0]));
    int bi = 0;
    for (int q = 1; q < 50; q++) {
      float m = fminf(gload(&fitB[b * 50 + q]), gload(&tfitB[b * 50 + q]));
      if (m < best) { best = m; bi = q; }
    }
    int bq = b * 50 + bi;
    bool useT = gload(&tfitB[bq]) < gload(&fitB[bq]);
    float v[6];
#pragma unroll
    for (int d = 0; d < 6; d++)
      v[d] = useT ? gload(&trialB[bq * 6 + d]) : gload(&popB[bq * 6 + d]);
    float R[3][3];
    compute_R(v[0], v[1], v[2], R);
#pragma unroll
    for (int i = 0; i < 3; i++)
#pragma unroll
      for (int j = 0; j < 3; j++) {
        gstore(&Rbest[b * 12 + i * 3 + j], R[i][j]);
        out[b * 9 + i * 3 + j] = R[i][j];
      }
#pragma unroll
    for (int d = 0; d < 3; d++) {
      gstore(&Rbest[b * 12 + 9 + d], v[3 + d]);
      out[288 + b * 3 + d] = v[3 + d];
    }
    __hip_atomic_fetch_add(&bar[b], 1u, __ATOMIC_RELEASE,
                           __HIP_MEMORY_SCOPE_AGENT);
  }
  if (tid == 0) {
    while (__hip_atomic_load(&bar[b], __ATOMIC_ACQUIRE,
                             __HIP_MEMORY_SCOPE_AGENT) < 1501u)
      __builtin_amdgcn_s_sleep(2);
  }
  __syncthreads();
  if (tid < 12) Rsh2[tid] = gload(&Rbest[b * 12 + tid]);
  __syncthreads();

  // ==== aligned transform: batch b's 16384 points across its 50 blocks ====
  for (int k = p * 128 + tid; k < 16384; k += 6400) {
    size_t gid = (size_t)b * 16384 + k;
    float a0s = source[gid * 3 + 0];
    float a1s = source[gid * 3 + 1];
    float a2s = source[gid * 3 + 2];
    float a0 = fmaf(Rsh2[2], a2s, fmaf(Rsh2[1], a1s, Rsh2[0] * a0s)) + Rsh2[9];
    float a1 = fmaf(Rsh2[5], a2s, fmaf(Rsh2[4], a1s, Rsh2[3] * a0s)) + Rsh2[10];
    float a2 = fmaf(Rsh2[8], a2s, fmaf(Rsh2[7], a1s, Rsh2[6] * a0s)) + Rsh2[11];
    out[384 + gid * 3 + 0] = a0;
    out[384 + gid * 3 + 1] = a1;
    out[384 + gid * 3 + 2] = a2;
  }
}

// ============================================================================
extern "C" void kernel_launch(void* const* d_in, const int* in_sizes, int n_in,
                              void* d_out, int out_size, void* d_ws,
                              size_t ws_size, hipStream_t stream) {
  const float* source = (const float*)d_in[0];
  const float* target = (const float*)d_in[1];
  float* out = (float*)d_out;
  char* ws = (char*)d_ws;

  // --- workspace layout, fully disjoint ---
  unsigned long long* sorted = (unsigned long long*)(ws + 0);   // 524288
  unsigned* rank_all = (unsigned*)(ws + 524288);                // 262144
  unsigned* x1buf    = (unsigned*)(ws + 786432);                // 131072
  int* idx           = (int*)(ws + 917504);                     // 1024
  unsigned* hist     = (unsigned*)(ws + 918528);                // 4096
  unsigned* bar      = (unsigned*)(ws + 922624);                // 128
  unsigned* basep    = (unsigned*)(ws + 922752);                // 4096
  unsigned* cursor   = (unsigned*)(ws + 926848);                // 4096
  unsigned* packg    = (unsigned*)(ws + 930944);                // 192000
  float* srcb        = (float*)(ws + 1122944);                  // 49152
  float* tgtb        = (float*)(ws + 1172096);                  // 49152
  float* ynb         = (float*)(ws + 1221248);                  // 16384
  float* popA        = (float*)(ws + 1237632);                  // 38400
  float* fitA        = (float*)(ws + 1276032);                  // 6400
  float* trialA      = (float*)(ws + 1282432);                  // 38400
  float* tfitA       = (float*)(ws + 1320832);                  // 6400
  float* popB        = (float*)(ws + 1327232);                  // 38400
  float* fitB        = (float*)(ws + 1365632);                  // 6400
  float* trialB      = (float*)(ws + 1372032);                  // 38400
  float* tfitB       = (float*)(ws + 1410432);                  // 6400
  float* Rbest       = (float*)(ws + 1416832);                  // 1536

  hipMemsetAsync(hist, 0, 4224, stream);  // hist (4096) + bar (128)
  hist_kernel<<<256, 256, 0, stream>>>(hist);
  prefix_kernel<<<1, 256, 0, stream>>>(hist, basep, cursor);
  scatterb_kernel<<<256, 256, 0, stream>>>(cursor, sorted);
  rank_kernel<<<256, 256, 0, stream>>>(sorted, basep, hist, rank_all, x1buf);
  idx_kernel<<<128, 256, 0, stream>>>(rank_all, x1buf, idx);
  setupperm_kernel<<<992, 128, 0, stream>>>(source, target, idx, srcb, tgtb,
                                            ynb, packg);

  de_loop_kernel<<<1600, 128, 0, stream>>>(
      srcb, tgtb, ynb, packg, popA, fitA, trialA, tfitA, popB, fitB, trialB,
      tfitB, bar, Rbest, source, out);
}

// Round 3
// 996.570 us; speedup vs baseline: 5.0827x; 5.0827x over previous
//
#include <hip/hip_runtime.h>
#include <stdint.h>

// ============================================================================
// JAX threefry2x32 PRNG reproduction (partitionable semantics, verified R0).
// ============================================================================
struct U2 { unsigned a, b; };

__device__ __forceinline__ unsigned rotl32(unsigned v, int r) {
  return (v << r) | (v >> (32 - r));
}

__device__ __forceinline__ U2 tf(U2 k, unsigned x0, unsigned x1) {
  unsigned ks0 = k.a, ks1 = k.b, ks2 = k.a ^ k.b ^ 0x1BD11BDAu;
  x0 += ks0; x1 += ks1;
#define TFG(RA, RB, RC, RD, KA, KB, INC)                  \
  x0 += x1; x1 = rotl32(x1, RA); x1 ^= x0;                \
  x0 += x1; x1 = rotl32(x1, RB); x1 ^= x0;                \
  x0 += x1; x1 = rotl32(x1, RC); x1 ^= x0;                \
  x0 += x1; x1 = rotl32(x1, RD); x1 ^= x0;                \
  x0 += KA; x1 += KB + INC;
  TFG(13, 15, 26, 6, ks1, ks2, 1u)
  TFG(17, 29, 16, 24, ks2, ks0, 2u)
  TFG(13, 15, 26, 6, ks0, ks1, 3u)
  TFG(17, 29, 16, 24, ks1, ks2, 4u)
  TFG(13, 15, 26, 6, ks2, ks0, 5u)
#undef TFG
  U2 r; r.a = x0; r.b = x1; return r;
}

__device__ __forceinline__ U2 split_key(U2 key, int num, int j) {
  (void)num;
  return tf(key, 0u, (unsigned)j);
}
__device__ __forceinline__ unsigned random_bits(U2 key, int n, unsigned e) {
  (void)n;
  U2 r = tf(key, 0u, e);
  return r.a ^ r.b;
}

__device__ __forceinline__ U2 root_key() { U2 k; k.a = 0u; k.b = 42u; return k; }

__device__ __forceinline__ float jax_uniform(U2 key, int n, unsigned e,
                                             float minv, float maxv) {
  unsigned b = random_bits(key, n, e);
  float u = __uint_as_float((b >> 9) | 0x3f800000u) - 1.0f;
  float r = u * (maxv - minv) + minv;
  return fmaxf(minv, r);
}

#define ROTR 0.7853981633974483f

__device__ __forceinline__ void compute_R(float vx, float vy, float vz,
                                          float R[3][3]) {
  float nsq = vx * vx + vy * vy + vz * vz;
  float theta = sqrtf(nsq);
  if (theta < 1e-8f) {
    R[0][0] = 1.f; R[0][1] = 0.f; R[0][2] = 0.f;
    R[1][0] = 0.f; R[1][1] = 1.f; R[1][2] = 0.f;
    R[2][0] = 0.f; R[2][1] = 0.f; R[2][2] = 1.f;
    return;
  }
  float m = fmaxf(theta, 1e-8f);
  float kx = vx / m, ky = vy / m, kz = vz / m;
  float s = sinf(theta), c = cosf(theta);
  float K[3][3] = {{0.f, -kz, ky}, {kz, 0.f, -kx}, {-ky, kx, 0.f}};
  float K2[3][3];
#pragma unroll
  for (int i = 0; i < 3; i++)
#pragma unroll
    for (int j = 0; j < 3; j++)
      K2[i][j] = fmaf(K[i][2], K[2][j], fmaf(K[i][1], K[1][j], K[i][0] * K[0][j]));
  float omc = 1.0f - c;
#pragma unroll
  for (int i = 0; i < 3; i++)
#pragma unroll
    for (int j = 0; j < 3; j++)
      R[i][j] = ((i == j) ? 1.0f : 0.0f) + s * K[i][j] + omc * K2[i][j];
}

// composite sort key for stream s (0:src r1, 1:src r2, 2:tgt r1, 3:tgt r2)
__device__ __forceinline__ unsigned long long make_composite(int s, int i) {
  U2 root = root_key();
  U2 kp = split_key(root, 5, s >> 1);
  U2 key;
  if ((s & 1) == 0) {
    key = split_key(kp, 2, 1);
  } else {
    U2 kA = split_key(kp, 2, 0);
    key = split_key(kA, 2, 1);
  }
  unsigned rb = random_bits(key, 16384, (unsigned)i);
  return ((unsigned long long)rb << 32) | (unsigned)i;
}

// ============================================================================
// Agent-scope access helpers — cross-block communication bypasses the
// non-coherent per-CU L1 / per-XCD L2 (coherence point = LLC/memory).
// ============================================================================
__device__ __forceinline__ float gload(const float* p) {
  return __hip_atomic_load(const_cast<float*>(p), __ATOMIC_RELAXED,
                           __HIP_MEMORY_SCOPE_AGENT);
}
__device__ __forceinline__ void gstore(float* p, float v) {
  __hip_atomic_store(p, v, __ATOMIC_RELAXED, __HIP_MEMORY_SCOPE_AGENT);
}
__device__ __forceinline__ unsigned uload(const unsigned* p) {
  return __hip_atomic_load(const_cast<unsigned*>(p), __ATOMIC_RELAXED,
                           __HIP_MEMORY_SCOPE_AGENT);
}
__device__ __forceinline__ void ustore(unsigned* p, unsigned v) {
  __hip_atomic_store(p, v, __ATOMIC_RELAXED, __HIP_MEMORY_SCOPE_AGENT);
}

// ============================================================================
// Bucket-sort rank pipeline (verified R3-R6/R10) — WIDE dispatches.
// ============================================================================
__global__ __launch_bounds__(256) void hist_kernel(unsigned* __restrict__ hist) {
  int gid = blockIdx.x * 256 + threadIdx.x;  // 65536
  int s = gid >> 14, i = gid & 16383;
  unsigned long long c = make_composite(s, i);
  unsigned bucket = (unsigned)(c >> 56);
  atomicAdd(&hist[s * 256 + bucket], 1u);
}

__global__ __launch_bounds__(256) void prefix_kernel(
    const unsigned* __restrict__ hist, unsigned* __restrict__ base,
    unsigned* __restrict__ cursor) {
  __shared__ unsigned h[4][256];
  int t = threadIdx.x;
#pragma unroll
  for (int s = 0; s < 4; s++) h[s][t] = hist[s * 256 + t];
  __syncthreads();
#pragma unroll
  for (int s = 0; s < 4; s++) {
    unsigned acc = 0;
    for (int j = 0; j < 256; j++) acc += (j < t) ? h[s][j] : 0u;
    base[s * 256 + t] = acc;
    cursor[s * 256 + t] = acc;
  }
}

__global__ __launch_bounds__(256) void scatterb_kernel(
    unsigned* __restrict__ cursor, unsigned long long* __restrict__ sorted) {
  int gid = blockIdx.x * 256 + threadIdx.x;  // 65536
  int s = gid >> 14, i = gid & 16383;
  unsigned long long c = make_composite(s, i);
  unsigned bucket = (unsigned)(c >> 56);
  unsigned pos = atomicAdd(&cursor[s * 256 + bucket], 1u);
  sorted[(s << 14) + pos] = c;
}

__global__ __launch_bounds__(256) void rank_kernel(
    const unsigned long long* __restrict__ sorted,
    const unsigned* __restrict__ base, const unsigned* __restrict__ hist,
    unsigned* __restrict__ rank_all, unsigned* __restrict__ x1buf) {
  int gid = blockIdx.x * 256 + threadIdx.x;  // 65536
  int s = gid >> 14, k = gid & 16383;
  unsigned long long c = sorted[(s << 14) + k];
  unsigned bucket = (unsigned)(c >> 56);
  unsigned b0 = base[s * 256 + bucket];
  unsigned cnt = hist[s * 256 + bucket];
  unsigned less = 0;
  for (unsigned j = 0; j < cnt; j++)
    less += (sorted[(s << 14) + b0 + j] < c) ? 1u : 0u;
  unsigned i = (unsigned)(c & 0xffffffffull);
  unsigned rank = b0 + less;
  if ((s & 1) == 0) x1buf[((s >> 1) << 14) + rank] = i;
  else              rank_all[(s << 14) + i] = rank;
}

__global__ __launch_bounds__(256) void idx_kernel(
    const unsigned* __restrict__ rank_all, const unsigned* __restrict__ x1buf,
    int* __restrict__ idx) {
  int gid = blockIdx.x * 256 + threadIdx.x;  // 32768
  int perm = gid >> 14, i = gid & 16383;
  unsigned r = rank_all[((perm * 2 + 1) << 14) + i];
  if (r < 128u) idx[perm * 128 + (int)r] = (int)x1buf[(perm << 14) + i];
}

// ============================================================================
// setup (blocks 0..31) + DE-schedule precompute (blocks 32..991).
// ============================================================================
__global__ __launch_bounds__(128) void setupperm_kernel(
    const float* __restrict__ source, const float* __restrict__ target,
    const int* __restrict__ idx, float* __restrict__ src,
    float* __restrict__ tgt, float* __restrict__ yn,
    unsigned* __restrict__ packg) {
  int blk = blockIdx.x;
  int tid = threadIdx.x;
  if (blk < 32) {
    int b = blk;
    int is = idx[tid], it = idx[128 + tid];
#pragma unroll
    for (int d = 0; d < 3; d++)
      src[(b * 128 + tid) * 3 + d] = source[((size_t)b * 16384 + is) * 3 + d];
    float y0 = target[((size_t)b * 16384 + it) * 3 + 0];
    float y1 = target[((size_t)b * 16384 + it) * 3 + 1];
    float y2 = target[((size_t)b * 16384 + it) * 3 + 2];
    tgt[(b * 128 + tid) * 3 + 0] = y0;
    tgt[(b * 128 + tid) * 3 + 1] = y1;
    tgt[(b * 128 + tid) * 3 + 2] = y2;
    yn[b * 128 + tid] = y0 * y0 + y1 * y1 + y2 * y2;
    return;
  }
  int blk2 = blk - 32;  // 960
  int it = blk2 >> 5, b = blk2 & 31;
  __shared__ unsigned pbits[3][64];
  __shared__ int lperm[3][64];
  U2 root = root_key();
  U2 kloop = split_key(root, 5, 4);
  U2 kit = split_key(kloop, 30, it);
  U2 ka = split_key(kit, 3, 0);
  for (int e = tid; e < 150; e += 128) {
    int r = e / 50, q = e % 50;
    U2 pk = split_key(ka, 96, r * 32 + b);
    U2 sub = split_key(pk, 2, 1);
    pbits[r][q] = random_bits(sub, 50, (unsigned)q);
  }
  __syncthreads();
  for (int e = tid; e < 150; e += 128) {
    int r = e / 50, q = e % 50;
    unsigned bq = pbits[r][q];
    int cnt = 0;
    for (int j = 0; j < 50; j++) {
      unsigned bj = pbits[r][j];
      cnt += (bj < bq || (bj == bq && j < q)) ? 1 : 0;
    }
    lperm[r][cnt] = q;
  }
  __syncthreads();
  if (tid < 50) {
    int p = tid, bp = b * 50 + p;
    U2 kb = split_key(kit, 3, 1);
    U2 kc = split_key(kit, 3, 2);
    U2 kc1 = split_key(kc, 2, 0), kc2 = split_key(kc, 2, 1);
    unsigned hb = random_bits(kc1, 1600, (unsigned)bp);
    unsigned lb = random_bits(kc2, 1600, (unsigned)bp);
    int jr = (int)((((hb % 6u) * 4u) + (lb % 6u)) % 6u);
    unsigned mask = 0;
#pragma unroll
    for (int d = 0; d < 6; d++) {
      unsigned rb = random_bits(kb, 9600, (unsigned)(bp * 6 + d));
      float u = __uint_as_float((rb >> 9) | 0x3f800000u) - 1.0f;
      if ((u < 0.9f) || (d == jr)) mask |= (1u << d);
    }
    unsigned pack = (unsigned)lperm[0][p] | ((unsigned)lperm[1][p] << 6) |
                    ((unsigned)lperm[2][p] << 12) | (mask << 18);
    packg[(it * 32 + b) * 50 + p] = pack;
  }
}

// ============================================================================
// Chamfer eval core (verified R6 — bitwise identical d2/min/sum path).
// ============================================================================
__device__ __forceinline__ float eval_pose_core(
    float p0, float p1, float p2, float p3, float p4, float p5,
    float s0, float s1, float s2, int tid, const float4* syv, float4* xsv,
    float* rowpart, float* red1, float* red2) {
  float Rm[3][3];
  compute_R(p0, p1, p2, Rm);
  float x0 = fmaf(Rm[0][2], s2, fmaf(Rm[0][1], s1, Rm[0][0] * s0)) + p3;
  float x1 = fmaf(Rm[1][2], s2, fmaf(Rm[1][1], s1, Rm[1][0] * s0)) + p4;
  float x2 = fmaf(Rm[2][2], s2, fmaf(Rm[2][1], s1, Rm[2][0] * s0)) + p5;
  float xn = x0 * x0 + x1 * x1 + x2 * x2;
  xsv[tid] = make_float4(x0, x1, x2, xn);
  __syncthreads();
  int rg = tid & 31, cq = tid >> 5;
  float4 xr0 = xsv[4 * rg + 0];
  float4 xr1 = xsv[4 * rg + 1];
  float4 xr2 = xsv[4 * rg + 2];
  float4 xr3 = xsv[4 * rg + 3];
  float racc0 = 3.402823466e38f, racc1 = 3.402823466e38f;
  float racc2 = 3.402823466e38f, racc3 = 3.402823466e38f;
  float cacc[32];
#pragma unroll
  for (int cj = 0; cj < 32; cj++) {
    float4 y = syv[(cq << 5) + cj];
    float cr0 = fmaf(xr0.z, y.z, fmaf(xr0.y, y.y, xr0.x * y.x));
    float d0 = (xr0.w + y.w) - 2.0f * cr0; d0 = fmaxf(d0, 0.0f);
    float cr1 = fmaf(xr1.z, y.z, fmaf(xr1.y, y.y, xr1.x * y.x));
    float d1 = (xr1.w + y.w) - 2.0f * cr1; d1 = fmaxf(d1, 0.0f);
    float cr2 = fmaf(xr2.z, y.z, fmaf(xr2.y, y.y, xr2.x * y.x));
    float d2_ = (xr2.w + y.w) - 2.0f * cr2; d2_ = fmaxf(d2_, 0.0f);
    float cr3 = fmaf(xr3.z, y.z, fmaf(xr3.y, y.y, xr3.x * y.x));
    float d3 = (xr3.w + y.w) - 2.0f * cr3; d3 = fmaxf(d3, 0.0f);
    racc0 = fminf(racc0, d0); racc1 = fminf(racc1, d1);
    racc2 = fminf(racc2, d2_); racc3 = fminf(racc3, d3);
    cacc[cj] = fminf(fminf(d0, d1), fminf(d2_, d3));
  }
  rowpart[cq * 128 + 4 * rg + 0] = racc0;
  rowpart[cq * 128 + 4 * rg + 1] = racc1;
  rowpart[cq * 128 + 4 * rg + 2] = racc2;
  rowpart[cq * 128 + 4 * rg + 3] = racc3;
#pragma unroll
  for (int m = 16; m >= 1; m >>= 1) {
    bool hi = (rg & m) != 0;
#pragma unroll
    for (int j = 0; j < m; j++) {
      float lo_v = cacc[j], hi_v = cacc[j + m];
      float mine = hi ? hi_v : lo_v;
      float send = hi ? lo_v : hi_v;
      float recv = __shfl_xor(send, m, 64);
      cacc[j] = fminf(mine, recv);
    }
  }
  float colmin = cacc[0];
  __syncthreads();
  float rv = rowpart[tid];
  rv = fminf(rv, rowpart[128 + tid]);
  rv = fminf(rv, rowpart[256 + tid]);
  rv = fminf(rv, rowpart[384 + tid]);
  red1[tid] = rv;
  red2[tid] = colmin;
  __syncthreads();
  int l = tid & 63;
  float v1 = red1[l] + red1[l + 64];
  float v2 = red2[l] + red2[l + 64];
#pragma unroll
  for (int m = 32; m >= 1; m >>= 1) {
    v1 += __shfl_xor(v1, m, 64);
    v2 += __shfl_xor(v2, m, 64);
  }
  return v1 * 0.0078125f + v2 * 0.0078125f;
}

// pop0 value for particle r, dim d of batch b (pure function)
__device__ __forceinline__ float pop0_val(int b, int r, int d) {
  if (r == 0) return 0.0f;
  U2 root = root_key();
  unsigned ridx = (unsigned)((b * 50 + r) * 3 + (d % 3));
  if (d < 3) {
    U2 k2 = split_key(root, 5, 2);
    return jax_uniform(k2, 4800, ridx, -ROTR, ROTR);
  }
  U2 k3 = split_key(root, 5, 3);
  return jax_uniform(k3, 4800, ridx, -1.0f, 1.0f);
}

// ============================================================================
// Persistent kernel: all 30 DE iterations + final select/transform.
// Dataflow pipeline (R3): per-particle per-iteration published state
//   estate[k][bp][8] = {E_k[0..5], F_k, pad}  (never overwritten -> no ABA)
//   flags[bp*16]     = number of published slots (own 64B cacheline).
// A block at iteration k polls ONLY its 3 donors' flags (>= k), reads their
// E_{k-1}. No batch-wide barrier, no shared cachelines -> no XCD ping-pong.
// Residency by construction: __launch_bounds__(128,4) -> 8 blocks/CU,
// capacity 2048 >= grid 1600 -> all blocks resident, spin-free-of-deadlock.
// ============================================================================
__global__ __launch_bounds__(128, 4) void de_loop_kernel(
    const float* __restrict__ srcb, const float* __restrict__ tgtb,
    const float* __restrict__ ynb, const unsigned* __restrict__ packg,
    float* __restrict__ estate, unsigned* __restrict__ flags,
    const float* __restrict__ source, float* __restrict__ out) {
  int blk = blockIdx.x;
  int b = blk / 50, p = blk % 50;
  int bp = blk;
  int tid = threadIdx.x;
  __shared__ float strial[8];
  __shared__ float pv4[4][6];
  __shared__ float4 syv[128];
  __shared__ float4 xsv[128];
  __shared__ float rowpart[512];
  __shared__ float red1[128];
  __shared__ float red2[128];
  __shared__ float fl[52];
  __shared__ float Rsh2[12];

  {
    float y0 = tgtb[(b * 128 + tid) * 3 + 0];
    float y1 = tgtb[(b * 128 + tid) * 3 + 1];
    float y2 = tgtb[(b * 128 + tid) * 3 + 2];
    syv[tid] = make_float4(y0, y1, y2, ynb[b * 128 + tid]);
  }
  float s0 = srcb[(b * 128 + tid) * 3 + 0];
  float s1 = srcb[(b * 128 + tid) * 3 + 1];
  float s2 = srcb[(b * 128 + tid) * 3 + 2];

  float own_f = 0.0f;    // replicated across all threads (uniform updates)
  float own_e = 0.0f;    // valid in threads tid<6: dimension tid of E_k

  for (int it = 0; it < 30; it++) {
    unsigned pack = packg[(it * 32 + b) * 50 + p];
    int i1 = (int)(pack & 63u);
    int i2 = (int)((pack >> 6) & 63u);
    int i3 = (int)((pack >> 12) & 63u);
    unsigned mask = (pack >> 18) & 63u;

    if (it == 0) {
      if (tid < 24) {
        int u = tid / 6, d = tid % 6;
        int rows[4] = {p, i1, i2, i3};
        pv4[u][d] = pop0_val(b, rows[u], d);
      }
      __syncthreads();
      float f0 = eval_pose_core(pv4[0][0], pv4[0][1], pv4[0][2], pv4[0][3],
                                pv4[0][4], pv4[0][5],
                                s0, s1, s2, tid, syv, xsv, rowpart, red1, red2);
      if (tid < 6) {
        int d = tid;
        float mu = pv4[1][d] + 0.8f * (pv4[2][d] - pv4[3][d]);
        if (d < 3) mu = fminf(fmaxf(mu, -ROTR), ROTR);
        else       mu = fminf(fmaxf(mu, -1.0f), 1.0f);
        float pv = pv4[0][d];
        float tv = ((mask >> d) & 1u) ? mu : pv;
        strial[d] = tv;
      }
      __syncthreads();
      float tf0 = eval_pose_core(strial[0], strial[1], strial[2], strial[3],
                                 strial[4], strial[5],
                                 s0, s1, s2, tid, syv, xsv, rowpart, red1, red2);
      bool imp = tf0 < f0;
      own_f = imp ? tf0 : f0;
      if (tid < 6) own_e = imp ? strial[tid] : pv4[0][tid];
    } else {
      // ---- poll the 3 donors' flags (>= it) ----
      if (tid < 3) {
        int dq = (tid == 0) ? i1 : (tid == 1) ? i2 : i3;
        const unsigned* fp = &flags[(b * 50 + dq) * 16];
        while (uload(fp) < (unsigned)it) __builtin_amdgcn_s_sleep(2);
        __builtin_amdgcn_fence(__ATOMIC_ACQUIRE, "agent");
      }
      __syncthreads();
      if (tid < 6) {
        int d = tid;
        const float* eb = &estate[((size_t)(it - 1) * 1600 + b * 50) * 8];
        float x1v = gload(&eb[i1 * 8 + d]);
        float x2v = gload(&eb[i2 * 8 + d]);
        float x3v = gload(&eb[i3 * 8 + d]);
        float mu = x1v + 0.8f * (x2v - x3v);
        if (d < 3) mu = fminf(fmaxf(mu, -ROTR), ROTR);
        else       mu = fminf(fmaxf(mu, -1.0f), 1.0f);
        float tv = ((mask >> d) & 1u) ? mu : own_e;
        strial[d] = tv;
      }
      __syncthreads();
      float tfv = eval_pose_core(strial[0], strial[1], strial[2], strial[3],
                                 strial[4], strial[5],
                                 s0, s1, s2, tid, syv, xsv, rowpart, red1, red2);
      bool imp = tfv < own_f;
      own_f = imp ? tfv : own_f;
      if (tid < 6) own_e = imp ? strial[tid] : own_e;
    }

    // ---- publish slot it ----
    float* slot = &estate[((size_t)it * 1600 + bp) * 8];
    if (tid < 6) gstore(&slot[tid], own_e);
    if (tid == 6) gstore(&slot[6], own_f);
    __syncthreads();  // drain stores (vmcnt(0)) before flag release
    if (tid == 0) {
      __builtin_amdgcn_fence(__ATOMIC_RELEASE, "agent");
      ustore(&flags[bp * 16], (unsigned)(it + 1));
    }
  }

  // ==== final selection (redundant per block -> no extra sync hop) ====
  if (tid < 50) {
    const unsigned* fp = &flags[(b * 50 + tid) * 16];
    while (uload(fp) < 30u) __builtin_amdgcn_s_sleep(2);
    __builtin_amdgcn_fence(__ATOMIC_ACQUIRE, "agent");
    fl[tid] = gload(&estate[((size_t)29 * 1600 + b * 50 + tid) * 8 + 6]);
  }
  __syncthreads();
  if (tid == 0) {
    int bi = 0;
    float best = fl[0];
    for (int q = 1; q < 50; q++)
      if (fl[q] < best) { best = fl[q]; bi = q; }
    const float* ep = &estate[((size_t)29 * 1600 + b * 50 + bi) * 8];
    float v[6];
#pragma unroll
    for (int d = 0; d < 6; d++) v[d] = gload(&ep[d]);
    float R[3][3];
    compute_R(v[0], v[1], v[2], R);
#pragma unroll
    for (int i = 0; i < 3; i++)
#pragma unroll
      for (int j = 0; j < 3; j++) Rsh2[i * 3 + j] = R[i][j];
    Rsh2[9] = v[3]; Rsh2[10] = v[4]; Rsh2[11] = v[5];
    if (p == 0) {
#pragma unroll
      for (int e = 0; e < 9; e++) out[b * 9 + e] = Rsh2[e];
      out[288 + b * 3 + 0] = v[3];
      out[288 + b * 3 + 1] = v[4];
      out[288 + b * 3 + 2] = v[5];
    }
  }
  __syncthreads();

  // ==== aligned transform: batch b's 16384 points across its 50 blocks ====
  for (int k = p * 128 + tid; k < 16384; k += 6400) {
    size_t gid = (size_t)b * 16384 + k;
    float a0s = source[gid * 3 + 0];
    float a1s = source[gid * 3 + 1];
    float a2s = source[gid * 3 + 2];
    float a0 = fmaf(Rsh2[2], a2s, fmaf(Rsh2[1], a1s, Rsh2[0] * a0s)) + Rsh2[9];
    float a1 = fmaf(Rsh2[5], a2s, fmaf(Rsh2[4], a1s, Rsh2[3] * a0s)) + Rsh2[10];
    float a2 = fmaf(Rsh2[8], a2s, fmaf(Rsh2[7], a1s, Rsh2[6] * a0s)) + Rsh2[11];
    out[384 + gid * 3 + 0] = a0;
    out[384 + gid * 3 + 1] = a1;
    out[384 + gid * 3 + 2] = a2;
  }
}

// ============================================================================
extern "C" void kernel_launch(void* const* d_in, const int* in_sizes, int n_in,
                              void* d_out, int out_size, void* d_ws,
                              size_t ws_size, hipStream_t stream) {
  const float* source = (const float*)d_in[0];
  const float* target = (const float*)d_in[1];
  float* out = (float*)d_out;
  char* ws = (char*)d_ws;

  // --- workspace layout ---
  // persistent (live during de_loop):
  unsigned* packg    = (unsigned*)(ws + 0);         // 192000
  float* srcb        = (float*)(ws + 192000);       // 49152
  float* tgtb        = (float*)(ws + 241152);       // 49152
  float* ynb         = (float*)(ws + 290304);       // 16384
  int* idx           = (int*)(ws + 306688);         // 1024
  unsigned* hist     = (unsigned*)(ws + 307712);    // 4096
  unsigned* flags    = (unsigned*)(ws + 311808);    // 102400 (1600 x 64B)
  unsigned* basep    = (unsigned*)(ws + 414208);    // 4096
  unsigned* cursor   = (unsigned*)(ws + 418304);    // 4096
  // sort scratch (dead after setup chain) overlaid by estate (stream-ordered):
  unsigned long long* sorted = (unsigned long long*)(ws + 422400);  // 524288
  unsigned* rank_all = (unsigned*)(ws + 946688);    // 262144
  unsigned* x1buf    = (unsigned*)(ws + 1208832);   // 131072
  float* estate      = (float*)(ws + 422400);       // 1536000 (overlay)

  hipMemsetAsync(hist, 0, 106496, stream);  // hist (4096) + flags (102400)
  hist_kernel<<<256, 256, 0, stream>>>(hist);
  prefix_kernel<<<1, 256, 0, stream>>>(hist, basep, cursor);
  scatterb_kernel<<<256, 256, 0, stream>>>(cursor, sorted);
  rank_kernel<<<256, 256, 0, stream>>>(sorted, basep, hist, rank_all, x1buf);
  idx_kernel<<<128, 256, 0, stream>>>(rank_all, x1buf, idx);
  setupperm_kernel<<<992, 128, 0, stream>>>(source, target, idx, srcb, tgtb,
                                            ynb, packg);

  de_loop_kernel<<<1600, 128, 0, stream>>>(srcb, tgtb, ynb, packg, estate,
                                           flags, source, out);
}

// Round 4
// 362.371 us; speedup vs baseline: 13.9781x; 2.7501x over previous
//
#include <hip/hip_runtime.h>
#include <stdint.h>

// ============================================================================
// JAX threefry2x32 PRNG reproduction (partitionable semantics, verified R0).
// ============================================================================
struct U2 { unsigned a, b; };

__device__ __forceinline__ unsigned rotl32(unsigned v, int r) {
  return (v << r) | (v >> (32 - r));
}

__device__ __forceinline__ U2 tf(U2 k, unsigned x0, unsigned x1) {
  unsigned ks0 = k.a, ks1 = k.b, ks2 = k.a ^ k.b ^ 0x1BD11BDAu;
  x0 += ks0; x1 += ks1;
#define TFG(RA, RB, RC, RD, KA, KB, INC)                  \
  x0 += x1; x1 = rotl32(x1, RA); x1 ^= x0;                \
  x0 += x1; x1 = rotl32(x1, RB); x1 ^= x0;                \
  x0 += x1; x1 = rotl32(x1, RC); x1 ^= x0;                \
  x0 += x1; x1 = rotl32(x1, RD); x1 ^= x0;                \
  x0 += KA; x1 += KB + INC;
  TFG(13, 15, 26, 6, ks1, ks2, 1u)
  TFG(17, 29, 16, 24, ks2, ks0, 2u)
  TFG(13, 15, 26, 6, ks0, ks1, 3u)
  TFG(17, 29, 16, 24, ks1, ks2, 4u)
  TFG(13, 15, 26, 6, ks2, ks0, 5u)
#undef TFG
  U2 r; r.a = x0; r.b = x1; return r;
}

__device__ __forceinline__ U2 split_key(U2 key, int num, int j) {
  (void)num;
  return tf(key, 0u, (unsigned)j);
}
__device__ __forceinline__ unsigned random_bits(U2 key, int n, unsigned e) {
  (void)n;
  U2 r = tf(key, 0u, e);
  return r.a ^ r.b;
}

__device__ __forceinline__ U2 root_key() { U2 k; k.a = 0u; k.b = 42u; return k; }

__device__ __forceinline__ float jax_uniform(U2 key, int n, unsigned e,
                                             float minv, float maxv) {
  unsigned b = random_bits(key, n, e);
  float u = __uint_as_float((b >> 9) | 0x3f800000u) - 1.0f;
  float r = u * (maxv - minv) + minv;
  return fmaxf(minv, r);
}

#define ROTR 0.7853981633974483f

__device__ __forceinline__ void compute_R(float vx, float vy, float vz,
                                          float R[3][3]) {
  float nsq = vx * vx + vy * vy + vz * vz;
  float theta = sqrtf(nsq);
  if (theta < 1e-8f) {
    R[0][0] = 1.f; R[0][1] = 0.f; R[0][2] = 0.f;
    R[1][0] = 0.f; R[1][1] = 1.f; R[1][2] = 0.f;
    R[2][0] = 0.f; R[2][1] = 0.f; R[2][2] = 1.f;
    return;
  }
  float m = fmaxf(theta, 1e-8f);
  float kx = vx / m, ky = vy / m, kz = vz / m;
  float s = sinf(theta), c = cosf(theta);
  float K[3][3] = {{0.f, -kz, ky}, {kz, 0.f, -kx}, {-ky, kx, 0.f}};
  float K2[3][3];
#pragma unroll
  for (int i = 0; i < 3; i++)
#pragma unroll
    for (int j = 0; j < 3; j++)
      K2[i][j] = fmaf(K[i][2], K[2][j], fmaf(K[i][1], K[1][j], K[i][0] * K[0][j]));
  float omc = 1.0f - c;
#pragma unroll
  for (int i = 0; i < 3; i++)
#pragma unroll
    for (int j = 0; j < 3; j++)
      R[i][j] = ((i == j) ? 1.0f : 0.0f) + s * K[i][j] + omc * K2[i][j];
}

// composite sort key for stream s (0:src r1, 1:src r2, 2:tgt r1, 3:tgt r2)
__device__ __forceinline__ unsigned long long make_composite(int s, int i) {
  U2 root = root_key();
  U2 kp = split_key(root, 5, s >> 1);
  U2 key;
  if ((s & 1) == 0) {
    key = split_key(kp, 2, 1);
  } else {
    U2 kA = split_key(kp, 2, 0);
    key = split_key(kA, 2, 1);
  }
  unsigned rb = random_bits(key, 16384, (unsigned)i);
  return ((unsigned long long)rb << 32) | (unsigned)i;
}

// ============================================================================
// Agent-scope RELAXED access helpers. These bypass the non-coherent L1/L2
// and hit the LLC directly. Ordering is provided by __syncthreads() (which
// emits s_waitcnt vmcnt(0) before s_barrier), NOT by acquire/release fences:
// agent fences emit buffer_inv / buffer_wbl2 cache walks, and 96K of those
// per dispatch saturated the per-XCD L2 pipelines in R3 (905us, VALU 23%).
// ============================================================================
__device__ __forceinline__ float gload(const float* p) {
  return __hip_atomic_load(const_cast<float*>(p), __ATOMIC_RELAXED,
                           __HIP_MEMORY_SCOPE_AGENT);
}
__device__ __forceinline__ void gstore(float* p, float v) {
  __hip_atomic_store(p, v, __ATOMIC_RELAXED, __HIP_MEMORY_SCOPE_AGENT);
}
__device__ __forceinline__ unsigned uload(const unsigned* p) {
  return __hip_atomic_load(const_cast<unsigned*>(p), __ATOMIC_RELAXED,
                           __HIP_MEMORY_SCOPE_AGENT);
}
__device__ __forceinline__ void ustore(unsigned* p, unsigned v) {
  __hip_atomic_store(p, v, __ATOMIC_RELAXED, __HIP_MEMORY_SCOPE_AGENT);
}

// ============================================================================
// Bucket-sort rank pipeline (verified R3-R6/R10) — WIDE dispatches.
// ============================================================================
__global__ __launch_bounds__(256) void hist_kernel(unsigned* __restrict__ hist) {
  int gid = blockIdx.x * 256 + threadIdx.x;  // 65536
  int s = gid >> 14, i = gid & 16383;
  unsigned long long c = make_composite(s, i);
  unsigned bucket = (unsigned)(c >> 56);
  atomicAdd(&hist[s * 256 + bucket], 1u);
}

__global__ __launch_bounds__(256) void prefix_kernel(
    const unsigned* __restrict__ hist, unsigned* __restrict__ base,
    unsigned* __restrict__ cursor) {
  __shared__ unsigned h[4][256];
  int t = threadIdx.x;
#pragma unroll
  for (int s = 0; s < 4; s++) h[s][t] = hist[s * 256 + t];
  __syncthreads();
#pragma unroll
  for (int s = 0; s < 4; s++) {
    unsigned acc = 0;
    for (int j = 0; j < 256; j++) acc += (j < t) ? h[s][j] : 0u;
    base[s * 256 + t] = acc;
    cursor[s * 256 + t] = acc;
  }
}

__global__ __launch_bounds__(256) void scatterb_kernel(
    unsigned* __restrict__ cursor, unsigned long long* __restrict__ sorted) {
  int gid = blockIdx.x * 256 + threadIdx.x;  // 65536
  int s = gid >> 14, i = gid & 16383;
  unsigned long long c = make_composite(s, i);
  unsigned bucket = (unsigned)(c >> 56);
  unsigned pos = atomicAdd(&cursor[s * 256 + bucket], 1u);
  sorted[(s << 14) + pos] = c;
}

__global__ __launch_bounds__(256) void rank_kernel(
    const unsigned long long* __restrict__ sorted,
    const unsigned* __restrict__ base, const unsigned* __restrict__ hist,
    unsigned* __restrict__ rank_all, unsigned* __restrict__ x1buf) {
  int gid = blockIdx.x * 256 + threadIdx.x;  // 65536
  int s = gid >> 14, k = gid & 16383;
  unsigned long long c = sorted[(s << 14) + k];
  unsigned bucket = (unsigned)(c >> 56);
  unsigned b0 = base[s * 256 + bucket];
  unsigned cnt = hist[s * 256 + bucket];
  unsigned less = 0;
  for (unsigned j = 0; j < cnt; j++)
    less += (sorted[(s << 14) + b0 + j] < c) ? 1u : 0u;
  unsigned i = (unsigned)(c & 0xffffffffull);
  unsigned rank = b0 + less;
  if ((s & 1) == 0) x1buf[((s >> 1) << 14) + rank] = i;
  else              rank_all[(s << 14) + i] = rank;
}

__global__ __launch_bounds__(256) void idx_kernel(
    const unsigned* __restrict__ rank_all, const unsigned* __restrict__ x1buf,
    int* __restrict__ idx) {
  int gid = blockIdx.x * 256 + threadIdx.x;  // 32768
  int perm = gid >> 14, i = gid & 16383;
  unsigned r = rank_all[((perm * 2 + 1) << 14) + i];
  if (r < 128u) idx[perm * 128 + (int)r] = (int)x1buf[(perm << 14) + i];
}

// ============================================================================
// setup (blocks 0..31) + DE-schedule precompute (blocks 32..991).
// ============================================================================
__global__ __launch_bounds__(128) void setupperm_kernel(
    const float* __restrict__ source, const float* __restrict__ target,
    const int* __restrict__ idx, float* __restrict__ src,
    float* __restrict__ tgt, float* __restrict__ yn,
    unsigned* __restrict__ packg) {
  int blk = blockIdx.x;
  int tid = threadIdx.x;
  if (blk < 32) {
    int b = blk;
    int is = idx[tid], it = idx[128 + tid];
#pragma unroll
    for (int d = 0; d < 3; d++)
      src[(b * 128 + tid) * 3 + d] = source[((size_t)b * 16384 + is) * 3 + d];
    float y0 = target[((size_t)b * 16384 + it) * 3 + 0];
    float y1 = target[((size_t)b * 16384 + it) * 3 + 1];
    float y2 = target[((size_t)b * 16384 + it) * 3 + 2];
    tgt[(b * 128 + tid) * 3 + 0] = y0;
    tgt[(b * 128 + tid) * 3 + 1] = y1;
    tgt[(b * 128 + tid) * 3 + 2] = y2;
    yn[b * 128 + tid] = y0 * y0 + y1 * y1 + y2 * y2;
    return;
  }
  int blk2 = blk - 32;  // 960
  int it = blk2 >> 5, b = blk2 & 31;
  __shared__ unsigned pbits[3][64];
  __shared__ int lperm[3][64];
  U2 root = root_key();
  U2 kloop = split_key(root, 5, 4);
  U2 kit = split_key(kloop, 30, it);
  U2 ka = split_key(kit, 3, 0);
  for (int e = tid; e < 150; e += 128) {
    int r = e / 50, q = e % 50;
    U2 pk = split_key(ka, 96, r * 32 + b);
    U2 sub = split_key(pk, 2, 1);
    pbits[r][q] = random_bits(sub, 50, (unsigned)q);
  }
  __syncthreads();
  for (int e = tid; e < 150; e += 128) {
    int r = e / 50, q = e % 50;
    unsigned bq = pbits[r][q];
    int cnt = 0;
    for (int j = 0; j < 50; j++) {
      unsigned bj = pbits[r][j];
      cnt += (bj < bq || (bj == bq && j < q)) ? 1 : 0;
    }
    lperm[r][cnt] = q;
  }
  __syncthreads();
  if (tid < 50) {
    int p = tid, bp = b * 50 + p;
    U2 kb = split_key(kit, 3, 1);
    U2 kc = split_key(kit, 3, 2);
    U2 kc1 = split_key(kc, 2, 0), kc2 = split_key(kc, 2, 1);
    unsigned hb = random_bits(kc1, 1600, (unsigned)bp);
    unsigned lb = random_bits(kc2, 1600, (unsigned)bp);
    int jr = (int)((((hb % 6u) * 4u) + (lb % 6u)) % 6u);
    unsigned mask = 0;
#pragma unroll
    for (int d = 0; d < 6; d++) {
      unsigned rb = random_bits(kb, 9600, (unsigned)(bp * 6 + d));
      float u = __uint_as_float((rb >> 9) | 0x3f800000u) - 1.0f;
      if ((u < 0.9f) || (d == jr)) mask |= (1u << d);
    }
    unsigned pack = (unsigned)lperm[0][p] | ((unsigned)lperm[1][p] << 6) |
                    ((unsigned)lperm[2][p] << 12) | (mask << 18);
    packg[(it * 32 + b) * 50 + p] = pack;
  }
}

// ============================================================================
// Chamfer eval core (verified R6 — bitwise identical d2/min/sum path).
// ============================================================================
__device__ __forceinline__ float eval_pose_core(
    float p0, float p1, float p2, float p3, float p4, float p5,
    float s0, float s1, float s2, int tid, const float4* syv, float4* xsv,
    float* rowpart, float* red1, float* red2) {
  float Rm[3][3];
  compute_R(p0, p1, p2, Rm);
  float x0 = fmaf(Rm[0][2], s2, fmaf(Rm[0][1], s1, Rm[0][0] * s0)) + p3;
  float x1 = fmaf(Rm[1][2], s2, fmaf(Rm[1][1], s1, Rm[1][0] * s0)) + p4;
  float x2 = fmaf(Rm[2][2], s2, fmaf(Rm[2][1], s1, Rm[2][0] * s0)) + p5;
  float xn = x0 * x0 + x1 * x1 + x2 * x2;
  xsv[tid] = make_float4(x0, x1, x2, xn);
  __syncthreads();
  int rg = tid & 31, cq = tid >> 5;
  float4 xr0 = xsv[4 * rg + 0];
  float4 xr1 = xsv[4 * rg + 1];
  float4 xr2 = xsv[4 * rg + 2];
  float4 xr3 = xsv[4 * rg + 3];
  float racc0 = 3.402823466e38f, racc1 = 3.402823466e38f;
  float racc2 = 3.402823466e38f, racc3 = 3.402823466e38f;
  float cacc[32];
#pragma unroll
  for (int cj = 0; cj < 32; cj++) {
    float4 y = syv[(cq << 5) + cj];
    float cr0 = fmaf(xr0.z, y.z, fmaf(xr0.y, y.y, xr0.x * y.x));
    float d0 = (xr0.w + y.w) - 2.0f * cr0; d0 = fmaxf(d0, 0.0f);
    float cr1 = fmaf(xr1.z, y.z, fmaf(xr1.y, y.y, xr1.x * y.x));
    float d1 = (xr1.w + y.w) - 2.0f * cr1; d1 = fmaxf(d1, 0.0f);
    float cr2 = fmaf(xr2.z, y.z, fmaf(xr2.y, y.y, xr2.x * y.x));
    float d2_ = (xr2.w + y.w) - 2.0f * cr2; d2_ = fmaxf(d2_, 0.0f);
    float cr3 = fmaf(xr3.z, y.z, fmaf(xr3.y, y.y, xr3.x * y.x));
    float d3 = (xr3.w + y.w) - 2.0f * cr3; d3 = fmaxf(d3, 0.0f);
    racc0 = fminf(racc0, d0); racc1 = fminf(racc1, d1);
    racc2 = fminf(racc2, d2_); racc3 = fminf(racc3, d3);
    cacc[cj] = fminf(fminf(d0, d1), fminf(d2_, d3));
  }
  rowpart[cq * 128 + 4 * rg + 0] = racc0;
  rowpart[cq * 128 + 4 * rg + 1] = racc1;
  rowpart[cq * 128 + 4 * rg + 2] = racc2;
  rowpart[cq * 128 + 4 * rg + 3] = racc3;
#pragma unroll
  for (int m = 16; m >= 1; m >>= 1) {
    bool hi = (rg & m) != 0;
#pragma unroll
    for (int j = 0; j < m; j++) {
      float lo_v = cacc[j], hi_v = cacc[j + m];
      float mine = hi ? hi_v : lo_v;
      float send = hi ? lo_v : hi_v;
      float recv = __shfl_xor(send, m, 64);
      cacc[j] = fminf(mine, recv);
    }
  }
  float colmin = cacc[0];
  __syncthreads();
  float rv = rowpart[tid];
  rv = fminf(rv, rowpart[128 + tid]);
  rv = fminf(rv, rowpart[256 + tid]);
  rv = fminf(rv, rowpart[384 + tid]);
  red1[tid] = rv;
  red2[tid] = colmin;
  __syncthreads();
  int l = tid & 63;
  float v1 = red1[l] + red1[l + 64];
  float v2 = red2[l] + red2[l + 64];
#pragma unroll
  for (int m = 32; m >= 1; m >>= 1) {
    v1 += __shfl_xor(v1, m, 64);
    v2 += __shfl_xor(v2, m, 64);
  }
  return v1 * 0.0078125f + v2 * 0.0078125f;
}

// pop0 value for particle r, dim d of batch b (pure function)
__device__ __forceinline__ float pop0_val(int b, int r, int d) {
  if (r == 0) return 0.0f;
  U2 root = root_key();
  unsigned ridx = (unsigned)((b * 50 + r) * 3 + (d % 3));
  if (d < 3) {
    U2 k2 = split_key(root, 5, 2);
    return jax_uniform(k2, 4800, ridx, -ROTR, ROTR);
  }
  U2 k3 = split_key(root, 5, 3);
  return jax_uniform(k3, 4800, ridx, -1.0f, 1.0f);
}

// ============================================================================
// Persistent kernel: all 30 DE iterations + final select/transform.
// Dataflow pipeline (R3/R4): per-particle per-iteration published state
//   estate[k][bp][8] = {E_k[0..5], F_k, pad}  (write-once -> no ABA)
//   flags[bp*16]     = number of published slots (own 64B cacheline).
// Publish:  estate stores (relaxed agent) ; __syncthreads (drains vmcnt) ;
//           flag store (relaxed agent).          <- release without fences
// Consume:  poll flag (relaxed) ; __syncthreads ; estate loads (relaxed).
// All cross-block traffic bypasses L1/L2 (atomic agent ops) so NO cache-
// maintenance instructions are needed — R3's fences caused an L2
// invalidate/writeback storm that serialized all memory traffic.
// Residency by construction: __launch_bounds__(128,4) -> 8+ blocks/CU,
// capacity >= 2048 >= grid 1600 -> all blocks resident, spins can't deadlock.
// ============================================================================
__global__ __launch_bounds__(128, 4) void de_loop_kernel(
    const float* __restrict__ srcb, const float* __restrict__ tgtb,
    const float* __restrict__ ynb, const unsigned* __restrict__ packg,
    float* __restrict__ estate, unsigned* __restrict__ flags,
    const float* __restrict__ source, float* __restrict__ out) {
  int blk = blockIdx.x;
  int b = blk / 50, p = blk % 50;
  int bp = blk;
  int tid = threadIdx.x;
  __shared__ float strial[8];
  __shared__ float pv4[4][6];
  __shared__ float4 syv[128];
  __shared__ float4 xsv[128];
  __shared__ float rowpart[512];
  __shared__ float red1[128];
  __shared__ float red2[128];
  __shared__ float fl[52];
  __shared__ float Rsh2[12];

  {
    float y0 = tgtb[(b * 128 + tid) * 3 + 0];
    float y1 = tgtb[(b * 128 + tid) * 3 + 1];
    float y2 = tgtb[(b * 128 + tid) * 3 + 2];
    syv[tid] = make_float4(y0, y1, y2, ynb[b * 128 + tid]);
  }
  float s0 = srcb[(b * 128 + tid) * 3 + 0];
  float s1 = srcb[(b * 128 + tid) * 3 + 1];
  float s2 = srcb[(b * 128 + tid) * 3 + 2];

  float own_f = 0.0f;    // replicated across all threads (uniform updates)
  float own_e = 0.0f;    // valid in threads tid<6: dimension tid of E_k

  for (int it = 0; it < 30; it++) {
    unsigned pack = packg[(it * 32 + b) * 50 + p];
    int i1 = (int)(pack & 63u);
    int i2 = (int)((pack >> 6) & 63u);
    int i3 = (int)((pack >> 12) & 63u);
    unsigned mask = (pack >> 18) & 63u;

    if (it == 0) {
      if (tid < 24) {
        int u = tid / 6, d = tid % 6;
        int rows[4] = {p, i1, i2, i3};
        pv4[u][d] = pop0_val(b, rows[u], d);
      }
      __syncthreads();
      float f0 = eval_pose_core(pv4[0][0], pv4[0][1], pv4[0][2], pv4[0][3],
                                pv4[0][4], pv4[0][5],
                                s0, s1, s2, tid, syv, xsv, rowpart, red1, red2);
      if (tid < 6) {
        int d = tid;
        float mu = pv4[1][d] + 0.8f * (pv4[2][d] - pv4[3][d]);
        if (d < 3) mu = fminf(fmaxf(mu, -ROTR), ROTR);
        else       mu = fminf(fmaxf(mu, -1.0f), 1.0f);
        float pv = pv4[0][d];
        float tv = ((mask >> d) & 1u) ? mu : pv;
        strial[d] = tv;
      }
      __syncthreads();
      float tf0 = eval_pose_core(strial[0], strial[1], strial[2], strial[3],
                                 strial[4], strial[5],
                                 s0, s1, s2, tid, syv, xsv, rowpart, red1, red2);
      bool imp = tf0 < f0;
      own_f = imp ? tf0 : f0;
      if (tid < 6) own_e = imp ? strial[tid] : pv4[0][tid];
    } else {
      // ---- poll the 3 donors' flags (>= it); relaxed loads, no fence ----
      if (tid < 3) {
        int dq = (tid == 0) ? i1 : (tid == 1) ? i2 : i3;
        const unsigned* fp = &flags[(b * 50 + dq) * 16];
        while (uload(fp) < (unsigned)it) __builtin_amdgcn_s_sleep(1);
      }
      __syncthreads();  // orders the poll before the estate loads below
      if (tid < 6) {
        int d = tid;
        const float* eb = &estate[((size_t)(it - 1) * 1600 + b * 50) * 8];
        float x1v = gload(&eb[i1 * 8 + d]);
        float x2v = gload(&eb[i2 * 8 + d]);
        float x3v = gload(&eb[i3 * 8 + d]);
        float mu = x1v + 0.8f * (x2v - x3v);
        if (d < 3) mu = fminf(fmaxf(mu, -ROTR), ROTR);
        else       mu = fminf(fmaxf(mu, -1.0f), 1.0f);
        float tv = ((mask >> d) & 1u) ? mu : own_e;
        strial[d] = tv;
      }
      __syncthreads();
      float tfv = eval_pose_core(strial[0], strial[1], strial[2], strial[3],
                                 strial[4], strial[5],
                                 s0, s1, s2, tid, syv, xsv, rowpart, red1, red2);
      bool imp = tfv < own_f;
      own_f = imp ? tfv : own_f;
      if (tid < 6) own_e = imp ? strial[tid] : own_e;
    }

    // ---- publish slot it (release via barrier's vmcnt(0) drain) ----
    float* slot = &estate[((size_t)it * 1600 + bp) * 8];
    if (tid < 6) gstore(&slot[tid], own_e);
    if (tid == 6) gstore(&slot[6], own_f);
    __syncthreads();  // s_waitcnt vmcnt(0) before s_barrier: stores at LLC
    if (tid == 0) ustore(&flags[bp * 16], (unsigned)(it + 1));
  }

  // ==== final selection (redundant per block -> no extra sync hop) ====
  if (tid < 50) {
    const unsigned* fp = &flags[(b * 50 + tid) * 16];
    while (uload(fp) < 30u) __builtin_amdgcn_s_sleep(1);
    fl[tid] = gload(&estate[((size_t)29 * 1600 + b * 50 + tid) * 8 + 6]);
  }
  __syncthreads();
  if (tid == 0) {
    int bi = 0;
    float best = fl[0];
    for (int q = 1; q < 50; q++)
      if (fl[q] < best) { best = fl[q]; bi = q; }
    const float* ep = &estate[((size_t)29 * 1600 + b * 50 + bi) * 8];
    float v[6];
#pragma unroll
    for (int d = 0; d < 6; d++) v[d] = gload(&ep[d]);
    float R[3][3];
    compute_R(v[0], v[1], v[2], R);
#pragma unroll
    for (int i = 0; i < 3; i++)
#pragma unroll
      for (int j = 0; j < 3; j++) Rsh2[i * 3 + j] = R[i][j];
    Rsh2[9] = v[3]; Rsh2[10] = v[4]; Rsh2[11] = v[5];
    if (p == 0) {
#pragma unroll
      for (int e = 0; e < 9; e++) out[b * 9 + e] = Rsh2[e];
      out[288 + b * 3 + 0] = v[3];
      out[288 + b * 3 + 1] = v[4];
      out[288 + b * 3 + 2] = v[5];
    }
  }
  __syncthreads();

  // ==== aligned transform: batch b's 16384 points across its 50 blocks ====
  for (int k = p * 128 + tid; k < 16384; k += 6400) {
    size_t gid = (size_t)b * 16384 + k;
    float a0s = source[gid * 3 + 0];
    float a1s = source[gid * 3 + 1];
    float a2s = source[gid * 3 + 2];
    float a0 = fmaf(Rsh2[2], a2s, fmaf(Rsh2[1], a1s, Rsh2[0] * a0s)) + Rsh2[9];
    float a1 = fmaf(Rsh2[5], a2s, fmaf(Rsh2[4], a1s, Rsh2[3] * a0s)) + Rsh2[10];
    float a2 = fmaf(Rsh2[8], a2s, fmaf(Rsh2[7], a1s, Rsh2[6] * a0s)) + Rsh2[11];
    out[384 + gid * 3 + 0] = a0;
    out[384 + gid * 3 + 1] = a1;
    out[384 + gid * 3 + 2] = a2;
  }
}

// ============================================================================
extern "C" void kernel_launch(void* const* d_in, const int* in_sizes, int n_in,
                              void* d_out, int out_size, void* d_ws,
                              size_t ws_size, hipStream_t stream) {
  const float* source = (const float*)d_in[0];
  const float* target = (const float*)d_in[1];
  float* out = (float*)d_out;
  char* ws = (char*)d_ws;

  // --- workspace layout ---
  // persistent (live during de_loop):
  unsigned* packg    = (unsigned*)(ws + 0);         // 192000
  float* srcb        = (float*)(ws + 192000);       // 49152
  float* tgtb        = (float*)(ws + 241152);       // 49152
  float* ynb         = (float*)(ws + 290304);       // 16384
  int* idx           = (int*)(ws + 306688);         // 1024
  unsigned* hist     = (unsigned*)(ws + 307712);    // 4096
  unsigned* flags    = (unsigned*)(ws + 311808);    // 102400 (1600 x 64B)
  unsigned* basep    = (unsigned*)(ws + 414208);    // 4096
  unsigned* cursor   = (unsigned*)(ws + 418304);    // 4096
  // sort scratch (dead after setup chain) overlaid by estate (stream-ordered):
  unsigned long long* sorted = (unsigned long long*)(ws + 422400);  // 524288
  unsigned* rank_all = (unsigned*)(ws + 946688);    // 262144
  unsigned* x1buf    = (unsigned*)(ws + 1208832);   // 131072
  float* estate      = (float*)(ws + 422400);       // 1536000 (overlay)

  hipMemsetAsync(hist, 0, 106496, stream);  // hist (4096) + flags (102400)
  hist_kernel<<<256, 256, 0, stream>>>(hist);
  prefix_kernel<<<1, 256, 0, stream>>>(hist, basep, cursor);
  scatterb_kernel<<<256, 256, 0, stream>>>(cursor, sorted);
  rank_kernel<<<256, 256, 0, stream>>>(sorted, basep, hist, rank_all, x1buf);
  idx_kernel<<<128, 256, 0, stream>>>(rank_all, x1buf, idx);
  setupperm_kernel<<<992, 128, 0, stream>>>(source, target, idx, srcb, tgtb,
                                            ynb, packg);

  de_loop_kernel<<<1600, 128, 0, stream>>>(srcb, tgtb, ynb, packg, estate,
                                           flags, source, out);
}

// Round 5
// 362.363 us; speedup vs baseline: 13.9784x; 1.0000x over previous
//
#include <hip/hip_runtime.h>
#include <stdint.h>

// ============================================================================
// JAX threefry2x32 PRNG reproduction (partitionable semantics, verified R0).
// ============================================================================
struct U2 { unsigned a, b; };

__device__ __forceinline__ unsigned rotl32(unsigned v, int r) {
  return (v << r) | (v >> (32 - r));
}

__device__ __forceinline__ U2 tf(U2 k, unsigned x0, unsigned x1) {
  unsigned ks0 = k.a, ks1 = k.b, ks2 = k.a ^ k.b ^ 0x1BD11BDAu;
  x0 += ks0; x1 += ks1;
#define TFG(RA, RB, RC, RD, KA, KB, INC)                  \
  x0 += x1; x1 = rotl32(x1, RA); x1 ^= x0;                \
  x0 += x1; x1 = rotl32(x1, RB); x1 ^= x0;                \
  x0 += x1; x1 = rotl32(x1, RC); x1 ^= x0;                \
  x0 += x1; x1 = rotl32(x1, RD); x1 ^= x0;                \
  x0 += KA; x1 += KB + INC;
  TFG(13, 15, 26, 6, ks1, ks2, 1u)
  TFG(17, 29, 16, 24, ks2, ks0, 2u)
  TFG(13, 15, 26, 6, ks0, ks1, 3u)
  TFG(17, 29, 16, 24, ks1, ks2, 4u)
  TFG(13, 15, 26, 6, ks2, ks0, 5u)
#undef TFG
  U2 r; r.a = x0; r.b = x1; return r;
}

__device__ __forceinline__ U2 split_key(U2 key, int num, int j) {
  (void)num;
  return tf(key, 0u, (unsigned)j);
}
__device__ __forceinline__ unsigned random_bits(U2 key, int n, unsigned e) {
  (void)n;
  U2 r = tf(key, 0u, e);
  return r.a ^ r.b;
}

__device__ __forceinline__ U2 root_key() { U2 k; k.a = 0u; k.b = 42u; return k; }

__device__ __forceinline__ float jax_uniform(U2 key, int n, unsigned e,
                                             float minv, float maxv) {
  unsigned b = random_bits(key, n, e);
  float u = __uint_as_float((b >> 9) | 0x3f800000u) - 1.0f;
  float r = u * (maxv - minv) + minv;
  return fmaxf(minv, r);
}

#define ROTR 0.7853981633974483f
#define SENTINEL 0xFFFFFFFFu  // -NaN bit pattern; unreachable for all
                              // published values (clamped floats / positive
                              // fitness; arithmetic NaNs are 0x7FC00000)

__device__ __forceinline__ void compute_R(float vx, float vy, float vz,
                                          float R[3][3]) {
  float nsq = vx * vx + vy * vy + vz * vz;
  float theta = sqrtf(nsq);
  if (theta < 1e-8f) {
    R[0][0] = 1.f; R[0][1] = 0.f; R[0][2] = 0.f;
    R[1][0] = 0.f; R[1][1] = 1.f; R[1][2] = 0.f;
    R[2][0] = 0.f; R[2][1] = 0.f; R[2][2] = 1.f;
    return;
  }
  float m = fmaxf(theta, 1e-8f);
  float kx = vx / m, ky = vy / m, kz = vz / m;
  float s = sinf(theta), c = cosf(theta);
  float K[3][3] = {{0.f, -kz, ky}, {kz, 0.f, -kx}, {-ky, kx, 0.f}};
  float K2[3][3];
#pragma unroll
  for (int i = 0; i < 3; i++)
#pragma unroll
    for (int j = 0; j < 3; j++)
      K2[i][j] = fmaf(K[i][2], K[2][j], fmaf(K[i][1], K[1][j], K[i][0] * K[0][j]));
  float omc = 1.0f - c;
#pragma unroll
  for (int i = 0; i < 3; i++)
#pragma unroll
    for (int j = 0; j < 3; j++)
      R[i][j] = ((i == j) ? 1.0f : 0.0f) + s * K[i][j] + omc * K2[i][j];
}

// composite sort key for stream s (0:src r1, 1:src r2, 2:tgt r1, 3:tgt r2)
__device__ __forceinline__ unsigned long long make_composite(int s, int i) {
  U2 root = root_key();
  U2 kp = split_key(root, 5, s >> 1);
  U2 key;
  if ((s & 1) == 0) {
    key = split_key(kp, 2, 1);
  } else {
    U2 kA = split_key(kp, 2, 0);
    key = split_key(kA, 2, 1);
  }
  unsigned rb = random_bits(key, 16384, (unsigned)i);
  return ((unsigned long long)rb << 32) | (unsigned)i;
}

// ============================================================================
// Agent-scope RELAXED access helpers — bypass non-coherent L1/L2, hit LLC.
// NO acquire/release fences anywhere (R3 lesson: agent fences emit
// buffer_inv/buffer_wbl2 walks; 96K of them serialized all memory traffic).
// Ordering model (R5): write-once word-granular sentinel publication —
// a word is valid iff != SENTINEL; no cross-word ordering ever needed.
// ============================================================================
__device__ __forceinline__ float gload(const float* p) {
  return __hip_atomic_load(const_cast<float*>(p), __ATOMIC_RELAXED,
                           __HIP_MEMORY_SCOPE_AGENT);
}
__device__ __forceinline__ void gstore(float* p, float v) {
  __hip_atomic_store(p, v, __ATOMIC_RELAXED, __HIP_MEMORY_SCOPE_AGENT);
}
__device__ __forceinline__ unsigned uload(const unsigned* p) {
  return __hip_atomic_load(const_cast<unsigned*>(p), __ATOMIC_RELAXED,
                           __HIP_MEMORY_SCOPE_AGENT);
}

// poll a published word until it is valid (write-once, sentinel-initialized)
__device__ __forceinline__ float poll_word(const float* p) {
  const unsigned* up = (const unsigned*)p;
  unsigned v = uload(up);
  while (v == SENTINEL) v = uload(up);
  return __uint_as_float(v);
}

// ============================================================================
// Bucket-sort rank pipeline (verified R3-R6/R10) — WIDE dispatches.
// ============================================================================
__global__ __launch_bounds__(256) void hist_kernel(unsigned* __restrict__ hist) {
  int gid = blockIdx.x * 256 + threadIdx.x;  // 65536
  int s = gid >> 14, i = gid & 16383;
  unsigned long long c = make_composite(s, i);
  unsigned bucket = (unsigned)(c >> 56);
  atomicAdd(&hist[s * 256 + bucket], 1u);
}

__global__ __launch_bounds__(256) void prefix_kernel(
    const unsigned* __restrict__ hist, unsigned* __restrict__ base,
    unsigned* __restrict__ cursor) {
  __shared__ unsigned h[4][256];
  int t = threadIdx.x;
#pragma unroll
  for (int s = 0; s < 4; s++) h[s][t] = hist[s * 256 + t];
  __syncthreads();
#pragma unroll
  for (int s = 0; s < 4; s++) {
    unsigned acc = 0;
    for (int j = 0; j < 256; j++) acc += (j < t) ? h[s][j] : 0u;
    base[s * 256 + t] = acc;
    cursor[s * 256 + t] = acc;
  }
}

__global__ __launch_bounds__(256) void scatterb_kernel(
    unsigned* __restrict__ cursor, unsigned long long* __restrict__ sorted) {
  int gid = blockIdx.x * 256 + threadIdx.x;  // 65536
  int s = gid >> 14, i = gid & 16383;
  unsigned long long c = make_composite(s, i);
  unsigned bucket = (unsigned)(c >> 56);
  unsigned pos = atomicAdd(&cursor[s * 256 + bucket], 1u);
  sorted[(s << 14) + pos] = c;
}

__global__ __launch_bounds__(256) void rank_kernel(
    const unsigned long long* __restrict__ sorted,
    const unsigned* __restrict__ base, const unsigned* __restrict__ hist,
    unsigned* __restrict__ rank_all, unsigned* __restrict__ x1buf) {
  int gid = blockIdx.x * 256 + threadIdx.x;  // 65536
  int s = gid >> 14, k = gid & 16383;
  unsigned long long c = sorted[(s << 14) + k];
  unsigned bucket = (unsigned)(c >> 56);
  unsigned b0 = base[s * 256 + bucket];
  unsigned cnt = hist[s * 256 + bucket];
  unsigned less = 0;
  for (unsigned j = 0; j < cnt; j++)
    less += (sorted[(s << 14) + b0 + j] < c) ? 1u : 0u;
  unsigned i = (unsigned)(c & 0xffffffffull);
  unsigned rank = b0 + less;
  if ((s & 1) == 0) x1buf[((s >> 1) << 14) + rank] = i;
  else              rank_all[(s << 14) + i] = rank;
}

__global__ __launch_bounds__(256) void idx_kernel(
    const unsigned* __restrict__ rank_all, const unsigned* __restrict__ x1buf,
    int* __restrict__ idx) {
  int gid = blockIdx.x * 256 + threadIdx.x;  // 32768
  int perm = gid >> 14, i = gid & 16383;
  unsigned r = rank_all[((perm * 2 + 1) << 14) + i];
  if (r < 128u) idx[perm * 128 + (int)r] = (int)x1buf[(perm << 14) + i];
}

// ============================================================================
// setup (blocks 0..31) + DE-schedule precompute (blocks 32..991).
// ============================================================================
__global__ __launch_bounds__(128) void setupperm_kernel(
    const float* __restrict__ source, const float* __restrict__ target,
    const int* __restrict__ idx, float* __restrict__ src,
    float* __restrict__ tgt, float* __restrict__ yn,
    unsigned* __restrict__ packg) {
  int blk = blockIdx.x;
  int tid = threadIdx.x;
  if (blk < 32) {
    int b = blk;
    int is = idx[tid], it = idx[128 + tid];
#pragma unroll
    for (int d = 0; d < 3; d++)
      src[(b * 128 + tid) * 3 + d] = source[((size_t)b * 16384 + is) * 3 + d];
    float y0 = target[((size_t)b * 16384 + it) * 3 + 0];
    float y1 = target[((size_t)b * 16384 + it) * 3 + 1];
    float y2 = target[((size_t)b * 16384 + it) * 3 + 2];
    tgt[(b * 128 + tid) * 3 + 0] = y0;
    tgt[(b * 128 + tid) * 3 + 1] = y1;
    tgt[(b * 128 + tid) * 3 + 2] = y2;
    yn[b * 128 + tid] = y0 * y0 + y1 * y1 + y2 * y2;
    return;
  }
  int blk2 = blk - 32;  // 960
  int it = blk2 >> 5, b = blk2 & 31;
  __shared__ unsigned pbits[3][64];
  __shared__ int lperm[3][64];
  U2 root = root_key();
  U2 kloop = split_key(root, 5, 4);
  U2 kit = split_key(kloop, 30, it);
  U2 ka = split_key(kit, 3, 0);
  for (int e = tid; e < 150; e += 128) {
    int r = e / 50, q = e % 50;
    U2 pk = split_key(ka, 96, r * 32 + b);
    U2 sub = split_key(pk, 2, 1);
    pbits[r][q] = random_bits(sub, 50, (unsigned)q);
  }
  __syncthreads();
  for (int e = tid; e < 150; e += 128) {
    int r = e / 50, q = e % 50;
    unsigned bq = pbits[r][q];
    int cnt = 0;
    for (int j = 0; j < 50; j++) {
      unsigned bj = pbits[r][j];
      cnt += (bj < bq || (bj == bq && j < q)) ? 1 : 0;
    }
    lperm[r][cnt] = q;
  }
  __syncthreads();
  if (tid < 50) {
    int p = tid, bp = b * 50 + p;
    U2 kb = split_key(kit, 3, 1);
    U2 kc = split_key(kit, 3, 2);
    U2 kc1 = split_key(kc, 2, 0), kc2 = split_key(kc, 2, 1);
    unsigned hb = random_bits(kc1, 1600, (unsigned)bp);
    unsigned lb = random_bits(kc2, 1600, (unsigned)bp);
    int jr = (int)((((hb % 6u) * 4u) + (lb % 6u)) % 6u);
    unsigned mask = 0;
#pragma unroll
    for (int d = 0; d < 6; d++) {
      unsigned rb = random_bits(kb, 9600, (unsigned)(bp * 6 + d));
      float u = __uint_as_float((rb >> 9) | 0x3f800000u) - 1.0f;
      if ((u < 0.9f) || (d == jr)) mask |= (1u << d);
    }
    unsigned pack = (unsigned)lperm[0][p] | ((unsigned)lperm[1][p] << 6) |
                    ((unsigned)lperm[2][p] << 12) | (mask << 18);
    packg[(it * 32 + b) * 50 + p] = pack;
  }
}

// ============================================================================
// Chamfer eval core (verified R6 — bitwise identical d2/min/sum path).
// ============================================================================
__device__ __forceinline__ float eval_pose_core(
    float p0, float p1, float p2, float p3, float p4, float p5,
    float s0, float s1, float s2, int tid, const float4* syv, float4* xsv,
    float* rowpart, float* red1, float* red2) {
  float Rm[3][3];
  compute_R(p0, p1, p2, Rm);
  float x0 = fmaf(Rm[0][2], s2, fmaf(Rm[0][1], s1, Rm[0][0] * s0)) + p3;
  float x1 = fmaf(Rm[1][2], s2, fmaf(Rm[1][1], s1, Rm[1][0] * s0)) + p4;
  float x2 = fmaf(Rm[2][2], s2, fmaf(Rm[2][1], s1, Rm[2][0] * s0)) + p5;
  float xn = x0 * x0 + x1 * x1 + x2 * x2;
  xsv[tid] = make_float4(x0, x1, x2, xn);
  __syncthreads();
  int rg = tid & 31, cq = tid >> 5;
  float4 xr0 = xsv[4 * rg + 0];
  float4 xr1 = xsv[4 * rg + 1];
  float4 xr2 = xsv[4 * rg + 2];
  float4 xr3 = xsv[4 * rg + 3];
  float racc0 = 3.402823466e38f, racc1 = 3.402823466e38f;
  float racc2 = 3.402823466e38f, racc3 = 3.402823466e38f;
  float cacc[32];
#pragma unroll
  for (int cj = 0; cj < 32; cj++) {
    float4 y = syv[(cq << 5) + cj];
    float cr0 = fmaf(xr0.z, y.z, fmaf(xr0.y, y.y, xr0.x * y.x));
    float d0 = (xr0.w + y.w) - 2.0f * cr0; d0 = fmaxf(d0, 0.0f);
    float cr1 = fmaf(xr1.z, y.z, fmaf(xr1.y, y.y, xr1.x * y.x));
    float d1 = (xr1.w + y.w) - 2.0f * cr1; d1 = fmaxf(d1, 0.0f);
    float cr2 = fmaf(xr2.z, y.z, fmaf(xr2.y, y.y, xr2.x * y.x));
    float d2_ = (xr2.w + y.w) - 2.0f * cr2; d2_ = fmaxf(d2_, 0.0f);
    float cr3 = fmaf(xr3.z, y.z, fmaf(xr3.y, y.y, xr3.x * y.x));
    float d3 = (xr3.w + y.w) - 2.0f * cr3; d3 = fmaxf(d3, 0.0f);
    racc0 = fminf(racc0, d0); racc1 = fminf(racc1, d1);
    racc2 = fminf(racc2, d2_); racc3 = fminf(racc3, d3);
    cacc[cj] = fminf(fminf(d0, d1), fminf(d2_, d3));
  }
  rowpart[cq * 128 + 4 * rg + 0] = racc0;
  rowpart[cq * 128 + 4 * rg + 1] = racc1;
  rowpart[cq * 128 + 4 * rg + 2] = racc2;
  rowpart[cq * 128 + 4 * rg + 3] = racc3;
#pragma unroll
  for (int m = 16; m >= 1; m >>= 1) {
    bool hi = (rg & m) != 0;
#pragma unroll
    for (int j = 0; j < m; j++) {
      float lo_v = cacc[j], hi_v = cacc[j + m];
      float mine = hi ? hi_v : lo_v;
      float send = hi ? lo_v : hi_v;
      float recv = __shfl_xor(send, m, 64);
      cacc[j] = fminf(mine, recv);
    }
  }
  float colmin = cacc[0];
  __syncthreads();
  float rv = rowpart[tid];
  rv = fminf(rv, rowpart[128 + tid]);
  rv = fminf(rv, rowpart[256 + tid]);
  rv = fminf(rv, rowpart[384 + tid]);
  red1[tid] = rv;
  red2[tid] = colmin;
  __syncthreads();
  int l = tid & 63;
  float v1 = red1[l] + red1[l + 64];
  float v2 = red2[l] + red2[l + 64];
#pragma unroll
  for (int m = 32; m >= 1; m >>= 1) {
    v1 += __shfl_xor(v1, m, 64);
    v2 += __shfl_xor(v2, m, 64);
  }
  return v1 * 0.0078125f + v2 * 0.0078125f;
}

// pop0 value for particle r, dim d of batch b (pure function)
__device__ __forceinline__ float pop0_val(int b, int r, int d) {
  if (r == 0) return 0.0f;
  U2 root = root_key();
  unsigned ridx = (unsigned)((b * 50 + r) * 3 + (d % 3));
  if (d < 3) {
    U2 k2 = split_key(root, 5, 2);
    return jax_uniform(k2, 4800, ridx, -ROTR, ROTR);
  }
  U2 k3 = split_key(root, 5, 3);
  return jax_uniform(k3, 4800, ridx, -1.0f, 1.0f);
}

// ============================================================================
// Persistent kernel (R5): sentinel-word dataflow pipeline.
//   estate[it][bp][8] = {E[0..5], F, pad}; memset to 0xFF (SENTINEL) upfront.
//   A word is published the instant its relaxed store reaches the LLC;
//   consumers poll exactly the words they need (write-once => no ordering,
//   no flags, no fences, no publish barrier, no poll barrier).
// Per-iter critical path: poll(1 LLC round) -> barrier -> eval -> stores.
// Residency by construction: __launch_bounds__(128,4) -> 8 blocks/CU,
// capacity 2048 >= grid 1600 -> all blocks resident, spins can't deadlock.
// ============================================================================
__global__ __launch_bounds__(128, 4) void de_loop_kernel(
    const float* __restrict__ srcb, const float* __restrict__ tgtb,
    const float* __restrict__ ynb, const unsigned* __restrict__ packg,
    float* __restrict__ estate, const float* __restrict__ source,
    float* __restrict__ out) {
  int blk = blockIdx.x;
  int b = blk / 50, p = blk % 50;
  int bp = blk;
  int tid = threadIdx.x;
  __shared__ float strial[8];
  __shared__ float pv4[4][6];
  __shared__ float4 syv[128];
  __shared__ float4 xsv[128];
  __shared__ float rowpart[512];
  __shared__ float red1[128];
  __shared__ float red2[128];
  __shared__ float fl[52];
  __shared__ float Rsh2[12];

  {
    float y0 = tgtb[(b * 128 + tid) * 3 + 0];
    float y1 = tgtb[(b * 128 + tid) * 3 + 1];
    float y2 = tgtb[(b * 128 + tid) * 3 + 2];
    syv[tid] = make_float4(y0, y1, y2, ynb[b * 128 + tid]);
  }
  float s0 = srcb[(b * 128 + tid) * 3 + 0];
  float s1 = srcb[(b * 128 + tid) * 3 + 1];
  float s2 = srcb[(b * 128 + tid) * 3 + 2];

  float own_f = 0.0f;    // replicated across all threads (uniform updates)
  float own_e = 0.0f;    // valid in threads tid<6: dimension tid of E_k

  unsigned pack_next = packg[(0 * 32 + b) * 50 + p];

  for (int it = 0; it < 30; it++) {
    unsigned pack = pack_next;
    if (it < 29) pack_next = packg[((it + 1) * 32 + b) * 50 + p];  // prefetch
    int i1 = (int)(pack & 63u);
    int i2 = (int)((pack >> 6) & 63u);
    int i3 = (int)((pack >> 12) & 63u);
    unsigned mask = (pack >> 18) & 63u;

    if (it == 0) {
      if (tid < 24) {
        int u = tid / 6, d = tid % 6;
        int rows[4] = {p, i1, i2, i3};
        pv4[u][d] = pop0_val(b, rows[u], d);
      }
      __syncthreads();
      float f0 = eval_pose_core(pv4[0][0], pv4[0][1], pv4[0][2], pv4[0][3],
                                pv4[0][4], pv4[0][5],
                                s0, s1, s2, tid, syv, xsv, rowpart, red1, red2);
      if (tid < 6) {
        int d = tid;
        float mu = pv4[1][d] + 0.8f * (pv4[2][d] - pv4[3][d]);
        if (d < 3) mu = fminf(fmaxf(mu, -ROTR), ROTR);
        else       mu = fminf(fmaxf(mu, -1.0f), 1.0f);
        float pv = pv4[0][d];
        float tv = ((mask >> d) & 1u) ? mu : pv;
        strial[d] = tv;
      }
      __syncthreads();
      float tf0 = eval_pose_core(strial[0], strial[1], strial[2], strial[3],
                                 strial[4], strial[5],
                                 s0, s1, s2, tid, syv, xsv, rowpart, red1, red2);
      bool imp = tf0 < f0;
      own_f = imp ? tf0 : f0;
      if (tid < 6) own_e = imp ? strial[tid] : pv4[0][tid];
    } else {
      // ---- fused poll+read of the 3 donors' dim-d words (1 LLC round) ----
      if (tid < 6) {
        int d = tid;
        const float* eb = &estate[((size_t)(it - 1) * 1600 + b * 50) * 8];
        const unsigned* pa = (const unsigned*)&eb[i1 * 8 + d];
        const unsigned* pb = (const unsigned*)&eb[i2 * 8 + d];
        const unsigned* pc = (const unsigned*)&eb[i3 * 8 + d];
        unsigned va = uload(pa), vb = uload(pb), vc = uload(pc);
        while (va == SENTINEL || vb == SENTINEL || vc == SENTINEL) {
          va = uload(pa); vb = uload(pb); vc = uload(pc);
        }
        float x1v = __uint_as_float(va);
        float x2v = __uint_as_float(vb);
        float x3v = __uint_as_float(vc);
        float mu = x1v + 0.8f * (x2v - x3v);
        if (d < 3) mu = fminf(fmaxf(mu, -ROTR), ROTR);
        else       mu = fminf(fmaxf(mu, -1.0f), 1.0f);
        float tv = ((mask >> d) & 1u) ? mu : own_e;
        strial[d] = tv;
      }
      __syncthreads();  // strial visible to both waves
      float tfv = eval_pose_core(strial[0], strial[1], strial[2], strial[3],
                                 strial[4], strial[5],
                                 s0, s1, s2, tid, syv, xsv, rowpart, red1, red2);
      bool imp = tfv < own_f;
      own_f = imp ? tfv : own_f;
      if (tid < 6) own_e = imp ? strial[tid] : own_e;
    }

    // ---- publish slot it: fire-and-forget word stores (no drain/barrier) ---
    float* slot = &estate[((size_t)it * 1600 + bp) * 8];
    if (tid < 6)       gstore(&slot[tid], own_e);
    else if (tid == 6) gstore(&slot[6], own_f);
  }

  // ==== final selection (redundant per block -> no extra sync hop) ====
  if (tid < 50) {
    fl[tid] = poll_word(&estate[((size_t)29 * 1600 + b * 50 + tid) * 8 + 6]);
  }
  __syncthreads();
  if (tid == 0) {
    int bi = 0;
    float best = fl[0];
    for (int q = 1; q < 50; q++)
      if (fl[q] < best) { best = fl[q]; bi = q; }
    const float* ep = &estate[((size_t)29 * 1600 + b * 50 + bi) * 8];
    float v[6];
#pragma unroll
    for (int d = 0; d < 6; d++) v[d] = poll_word(&ep[d]);  // e/f unordered
    float R[3][3];
    compute_R(v[0], v[1], v[2], R);
#pragma unroll
    for (int i = 0; i < 3; i++)
#pragma unroll
      for (int j = 0; j < 3; j++) Rsh2[i * 3 + j] = R[i][j];
    Rsh2[9] = v[3]; Rsh2[10] = v[4]; Rsh2[11] = v[5];
    if (p == 0) {
#pragma unroll
      for (int e = 0; e < 9; e++) out[b * 9 + e] = Rsh2[e];
      out[288 + b * 3 + 0] = v[3];
      out[288 + b * 3 + 1] = v[4];
      out[288 + b * 3 + 2] = v[5];
    }
  }
  __syncthreads();

  // ==== aligned transform: batch b's 16384 points across its 50 blocks ====
  for (int k = p * 128 + tid; k < 16384; k += 6400) {
    size_t gid = (size_t)b * 16384 + k;
    float a0s = source[gid * 3 + 0];
    float a1s = source[gid * 3 + 1];
    float a2s = source[gid * 3 + 2];
    float a0 = fmaf(Rsh2[2], a2s, fmaf(Rsh2[1], a1s, Rsh2[0] * a0s)) + Rsh2[9];
    float a1 = fmaf(Rsh2[5], a2s, fmaf(Rsh2[4], a1s, Rsh2[3] * a0s)) + Rsh2[10];
    float a2 = fmaf(Rsh2[8], a2s, fmaf(Rsh2[7], a1s, Rsh2[6] * a0s)) + Rsh2[11];
    out[384 + gid * 3 + 0] = a0;
    out[384 + gid * 3 + 1] = a1;
    out[384 + gid * 3 + 2] = a2;
  }
}

// ============================================================================
extern "C" void kernel_launch(void* const* d_in, const int* in_sizes, int n_in,
                              void* d_out, int out_size, void* d_ws,
                              size_t ws_size, hipStream_t stream) {
  const float* source = (const float*)d_in[0];
  const float* target = (const float*)d_in[1];
  float* out = (float*)d_out;
  char* ws = (char*)d_ws;

  // --- workspace layout ---
  // persistent (live during de_loop):
  unsigned* packg    = (unsigned*)(ws + 0);         // 192000
  float* srcb        = (float*)(ws + 192000);       // 49152
  float* tgtb        = (float*)(ws + 241152);       // 49152
  float* ynb         = (float*)(ws + 290304);       // 16384
  int* idx           = (int*)(ws + 306688);         // 1024
  unsigned* hist     = (unsigned*)(ws + 307712);    // 4096
  unsigned* basep    = (unsigned*)(ws + 414208);    // 4096
  unsigned* cursor   = (unsigned*)(ws + 418304);    // 4096
  // sort scratch (dead after setup chain) overlaid by estate (stream-ordered):
  unsigned long long* sorted = (unsigned long long*)(ws + 422400);  // 524288
  unsigned* rank_all = (unsigned*)(ws + 946688);    // 262144
  unsigned* x1buf    = (unsigned*)(ws + 1208832);   // 131072
  float* estate      = (float*)(ws + 422400);       // 1536000 (overlay)

  hipMemsetAsync(hist, 0, 4096, stream);
  hist_kernel<<<256, 256, 0, stream>>>(hist);
  prefix_kernel<<<1, 256, 0, stream>>>(hist, basep, cursor);
  scatterb_kernel<<<256, 256, 0, stream>>>(cursor, sorted);
  rank_kernel<<<256, 256, 0, stream>>>(sorted, basep, hist, rank_all, x1buf);
  idx_kernel<<<128, 256, 0, stream>>>(rank_all, x1buf, idx);
  // sort scratch is dead from here; initialize estate to SENTINEL (0xFF bytes)
  hipMemsetAsync(estate, 0xFF, 1536000, stream);
  setupperm_kernel<<<992, 128, 0, stream>>>(source, target, idx, srcb, tgtb,
                                            ynb, packg);

  de_loop_kernel<<<1600, 128, 0, stream>>>(srcb, tgtb, ynb, packg, estate,
                                           source, out);
}